// Round 3
// baseline (2733.682 us; speedup 1.0000x reference)
//
#include <hip/hip_runtime.h>

// Problem dims
#define BB 4096
#define DD 2048
#define CC 1000

// ---------------------------------------------------------------------------
// Common wave-level reductions.  Single shared definition used by both
// stats_kernel and opt_kernel so iteration-1 of the optimizer reproduces
// p_trg bitwise (the reference gets sign(0)=0 there).
// ---------------------------------------------------------------------------
__device__ __forceinline__ void wave_argmax(float& val, int& idx) {
#pragma unroll
  for (int off = 1; off < 64; off <<= 1) {
    float ov = __shfl_xor(val, off, 64);
    int oi = __shfl_xor(idx, off, 64);
    if (ov > val || (ov == val && oi < idx)) { val = ov; idx = oi; }
  }
}

__device__ __forceinline__ float wave_sum(float v) {
#pragma unroll
  for (int off = 1; off < 64; off <<= 1) v += __shfl_xor(v, off, 64);
  return v;
}

// ---------------------------------------------------------------------------
// GEMM: Z = X @ W + b   (fp32, 64x64 tile, BK=16, 4x4 per thread)
// ---------------------------------------------------------------------------
__global__ __launch_bounds__(256) void gemm_kernel(
    const float* __restrict__ X, const float* __restrict__ W,
    const float* __restrict__ Bv, float* __restrict__ Z) {
  __shared__ float sA[16][68];
  __shared__ float sB[16][68];
  const int tid = threadIdx.x;
  const int rowTile = blockIdx.y * 64;
  const int colTile = blockIdx.x * 64;
  const int tx = tid & 15, ty = tid >> 4;
  float acc[4][4] = {};

  const int aRow = tid >> 2;        // 0..63
  const int aK = (tid & 3) << 2;    // 0,4,8,12
  const int bK = tid >> 4;          // 0..15
  const int bC = (tid & 15) << 2;   // 0..60
  const bool fullCol = (colTile + 64) <= CC;

  for (int k0 = 0; k0 < DD; k0 += 16) {
    const float4 av = *(const float4*)&X[(size_t)(rowTile + aRow) * DD + k0 + aK];
    sA[aK + 0][aRow] = av.x;
    sA[aK + 1][aRow] = av.y;
    sA[aK + 2][aRow] = av.z;
    sA[aK + 3][aRow] = av.w;
    float4 bv;
    if (fullCol) {
      bv = *(const float4*)&W[(size_t)(k0 + bK) * CC + colTile + bC];
    } else {
      const int c0 = colTile + bC;
      bv.x = (c0 + 0 < CC) ? W[(size_t)(k0 + bK) * CC + c0 + 0] : 0.f;
      bv.y = (c0 + 1 < CC) ? W[(size_t)(k0 + bK) * CC + c0 + 1] : 0.f;
      bv.z = (c0 + 2 < CC) ? W[(size_t)(k0 + bK) * CC + c0 + 2] : 0.f;
      bv.w = (c0 + 3 < CC) ? W[(size_t)(k0 + bK) * CC + c0 + 3] : 0.f;
    }
    *(float4*)&sB[bK][bC] = bv;
    __syncthreads();
#pragma unroll
    for (int kk = 0; kk < 16; ++kk) {
      const float4 a4 = *(const float4*)&sA[kk][ty << 2];
      const float4 b4 = *(const float4*)&sB[kk][tx << 2];
      const float ar[4] = {a4.x, a4.y, a4.z, a4.w};
      const float br[4] = {b4.x, b4.y, b4.z, b4.w};
#pragma unroll
      for (int i = 0; i < 4; ++i)
#pragma unroll
        for (int j = 0; j < 4; ++j) acc[i][j] = fmaf(ar[i], br[j], acc[i][j]);
    }
    __syncthreads();
  }
#pragma unroll
  for (int i = 0; i < 4; ++i) {
    const int r = rowTile + (ty << 2) + i;
#pragma unroll
    for (int j = 0; j < 4; ++j) {
      const int c = colTile + (tx << 2) + j;
      if (c < CC) Z[(size_t)r * CC + c] = acc[i][j] + Bv[c];
    }
  }
}

// ---------------------------------------------------------------------------
// Per-row stats from z: y = argmax, l_trg, p_trg.
// One wave per row; lane l owns columns l + 64*k, k = 0..15.
// ---------------------------------------------------------------------------
__global__ __launch_bounds__(256) void stats_kernel(
    const float* __restrict__ Z, int* __restrict__ Y,
    float* __restrict__ Lt, float* __restrict__ Pt) {
  const int wave = threadIdx.x >> 6, lane = threadIdx.x & 63;
  const int row = blockIdx.x * 4 + wave;
  float uv[16];
#pragma unroll
  for (int k = 0; k < 16; ++k) {
    const int j = lane + (k << 6);
    uv[k] = (j < CC) ? Z[(size_t)row * CC + j] : -__builtin_inff();
  }
  float mx = uv[0];
  int ai = lane;
#pragma unroll
  for (int k = 1; k < 16; ++k) {
    const int j = lane + (k << 6);
    if (uv[k] > mx) { mx = uv[k]; ai = j; }
  }
  wave_argmax(mx, ai);
  float sum = 0.f;
#pragma unroll
  for (int k = 0; k < 16; ++k) sum += expf(uv[k] - mx);
  sum = wave_sum(sum);
  if (lane == 0) {
    const float lse = mx + logf(sum);
    const float lorg = lse - mx;  // == lse - z[y]
    const float latr = (floorf(lorg / 6.0f) + 0.5f) * 6.0f;
    const float lt =
        lorg - 6.0f * sinf(3.14159265358979323846f *
                           (1.0f - 2.0f * (lorg - latr) / 6.0f));
    Y[row] = ai;
    Lt[row] = lt;
    Pt[row] = 1.0f / sum;  // max softmax = exp(max - lse) = 1/sum
  }
}

// ---------------------------------------------------------------------------
// Bitonic sort of p_trg (4096) in LDS, single block.
// ---------------------------------------------------------------------------
__global__ __launch_bounds__(1024) void sort_kernel(
    const float* __restrict__ P, float* __restrict__ Out) {
  __shared__ float s[4096];
  const int tid = threadIdx.x;
  for (int i = tid; i < 4096; i += 1024) s[i] = P[i];
  __syncthreads();
  for (int k = 2; k <= 4096; k <<= 1) {
    for (int j = k >> 1; j > 0; j >>= 1) {
      for (int i = tid; i < 4096; i += 1024) {
        const int ixj = i ^ j;
        if (ixj > i) {
          const float a = s[i], b = s[ixj];
          const bool up = ((i & k) == 0);
          if (up ? (a > b) : (a < b)) { s[i] = b; s[ixj] = a; }
        }
      }
      __syncthreads();
    }
  }
  for (int i = tid; i < 4096; i += 1024) Out[i] = s[i];
}

// ---------------------------------------------------------------------------
// Cooperative optimizer: 256 blocks x 1024 threads, 1 block/CU.
// One wave per row; u,m,v (and cached exp) live in registers for all 100
// iterations.
//
// Sync protocol (RELAXED atomics only — every cross-block datum is packed
// inside the one 64-bit slot word, so no fences are needed; the epoch tag
// provides protocol-level ordering):
//   - each block stores one epoch-tagged slot {pmax:32 | epoch:8 | row,col:22}
//     (parity double-buffered; a slot of epoch t is only overwritten at t+2,
//     after every block wrote t+1, which happens after every block finished
//     reading t — hang/tear-free).
//   - every block's wave 0 polls all 256 slots until epoch==t, computes the
//     global argmax + rank-query S locally.
//
// Latency hiding: only row r* (global argmax) receives the term2 gradient.
// All waves save (u,m,v) and apply the term1-only AdamW update immediately
// after the slot store (overlapping store visibility + others' phase A);
// after the poll, the single wave owning r* redoes its update from the saved
// state with the exact two-step gradient sum — bitwise identical to the
// sequential path.
// ---------------------------------------------------------------------------
__global__ __launch_bounds__(1024, 4) void opt_kernel(
    float* __restrict__ ZU, const int* __restrict__ Yarr,
    const float* __restrict__ Ltrg, const float* __restrict__ Sorted,
    unsigned long long* __restrict__ Slots) {
  const int tid = threadIdx.x;
  const int wave = tid >> 6, lane = tid & 63;
  const int row = blockIdx.x * 16 + wave;

  __shared__ float s_sorted[4096];
  __shared__ float s_cval[16];
  __shared__ int s_cidx[16];
  __shared__ float s_coef;
  __shared__ int s_rc;  // rstar<<10 | cstar

  for (int i = tid; i < 4096; i += 1024) s_sorted[i] = Sorted[i];

  float u[16], m[16], v[16], e[16];
#pragma unroll
  for (int k = 0; k < 16; ++k) {
    const int j = lane + (k << 6);
    u[k] = (j < CC) ? ZU[(size_t)row * CC + j] : -__builtin_inff();
    m[k] = 0.f;
    v[k] = 0.f;
  }
  const int y = Yarr[row];
  const float ltrg = Ltrg[row];
  const int ky = y >> 6, ly = y & 63;

  float pb1 = 1.0f, pb2 = 1.0f;
  __syncthreads();

#pragma unroll 1
  for (int t = 1; t <= 100; ++t) {
    pb1 *= 0.9f;
    pb2 *= 0.999f;
    const float im1 = 1.0f / (1.0f - pb1);
    const float im2 = 1.0f / (1.0f - pb2);

    // ---- Phase A: row stats (same arithmetic as stats_kernel) ----
    float mx = u[0];
    int ai = lane;
#pragma unroll
    for (int k = 1; k < 16; ++k) {
      const int j = lane + (k << 6);
      if (u[k] > mx) { mx = u[k]; ai = j; }
    }
    wave_argmax(mx, ai);
    float sum = 0.f;
#pragma unroll
    for (int k = 0; k < 16; ++k) {
      e[k] = expf(u[k] - mx);
      sum += e[k];
    }
    sum = wave_sum(sum);
    const float lse = mx + logf(sum);
    float uyl = 0.f;
#pragma unroll
    for (int k = 0; k < 16; ++k) uyl = (k == ky) ? u[k] : uyl;
    const float uy = __shfl(uyl, ly, 64);
    const float ce = lse - uy;
    const float pmax = 1.0f / sum;  // row max softmax

    if (lane == 0) {
      s_cval[wave] = pmax;
      s_cidx[wave] = (row << 10) | ai;
    }
    __syncthreads();

    unsigned long long* slot_buf = &Slots[(t & 1) * 256];
    if (tid == 0) {
      float bv = s_cval[0];
      int bi = s_cidx[0];
#pragma unroll
      for (int w = 1; w < 16; ++w) {
        const float ov = s_cval[w];
        const int oi = s_cidx[w];
        if (ov > bv || (ov == bv && oi < bi)) { bv = ov; bi = oi; }
      }
      const unsigned long long pack =
          ((unsigned long long)__float_as_uint(bv) << 32) |
          (unsigned)((t << 24) | bi);
      __hip_atomic_store(&slot_buf[blockIdx.x], pack, __ATOMIC_RELAXED,
                         __HIP_MEMORY_SCOPE_AGENT);
    }

    const float a = (ce > ltrg) ? 1.0f : ((ce < ltrg) ? -1.0f : 0.0f);

    // ---- speculative term1-only AdamW (saves old state for possible redo) --
    float u_old[16], m_old[16], v_old[16];
#pragma unroll
    for (int k = 0; k < 16; ++k) {
      const int j = lane + (k << 6);
      u_old[k] = u[k];
      m_old[k] = m[k];
      v_old[k] = v[k];
      const float p = e[k] * pmax;  // softmax(u)[j] = exp(u-mx)/sum
      const float g = a * (p - ((j == y) ? 1.0f : 0.0f));
      u[k] *= 0.999f;  // 1 - LR*WD
      m[k] = 0.9f * m[k] + 0.1f * g;
      v[k] = 0.999f * v[k] + 0.001f * g * g;
      const float mh = m[k] * im1;
      const float vh = v[k] * im2;
      u[k] -= (0.1f * mh) / (sqrtf(vh) + 1e-8f);
    }

    // ---- wave 0: poll all 256 slots, then global argmax + rank-query S ----
    if (wave == 0) {
      unsigned long long pv[4];
      unsigned fresh = 0u;
      while (fresh != 0xFu) {
#pragma unroll
        for (int q = 0; q < 4; ++q) {
          if (!(fresh & (1u << q))) {
            const unsigned long long p = __hip_atomic_load(
                &slot_buf[lane + (q << 6)], __ATOMIC_RELAXED,
                __HIP_MEMORY_SCOPE_AGENT);
            if ((unsigned)((p >> 24) & 0xFFu) == (unsigned)t) {
              pv[q] = p;
              fresh |= 1u << q;
            }
          }
        }
        if (fresh != 0xFu) __builtin_amdgcn_s_sleep(1);
      }
      float bv = -1.0f;
      int bi = 0x7fffffff;
#pragma unroll
      for (int q = 0; q < 4; ++q) {
        const float ov = __uint_as_float((unsigned)(pv[q] >> 32));
        const int oi = (int)(pv[q] & 0x3FFFFFu);
        if (ov > bv || (ov == bv && oi < bi)) { bv = ov; bi = oi; }
      }
      wave_argmax(bv, bi);
      const float ss = bv;
      // rank queries on sorted p_trg: S = #(p_trg < ss) - #(p_trg > ss)
      const float v1 = s_sorted[lane << 6];
      const int c1 = __popcll(__ballot(v1 < ss));
      int nlt = 0;
      if (c1 > 0) {
        const float v2 = s_sorted[((c1 - 1) << 6) + lane];
        nlt = ((c1 - 1) << 6) + __popcll(__ballot(v2 < ss));
      }
      const int c2 = __popcll(__ballot(v1 <= ss));
      int nle = 0;
      if (c2 > 0) {
        const float v3 = s_sorted[((c2 - 1) << 6) + lane];
        nle = ((c2 - 1) << 6) + __popcll(__ballot(v3 <= ss));
      }
      const int S = nlt - (4096 - nle);
      if (lane == 0) {
        s_coef = 5.0f * (float)S * ss;  // BETA * S * M
        s_rc = bi;
      }
    }
    __syncthreads();

    const int rc = s_rc;
    if (row == (rc >> 10)) {
      // ---- redo this row's update with the exact combined gradient ----
      const float coef = s_coef;
      const int cstar = rc & 1023;
#pragma unroll
      for (int k = 0; k < 16; ++k) {
        const int j = lane + (k << 6);
        const float p = e[k] * pmax;
        float g = a * (p - ((j == y) ? 1.0f : 0.0f));
        g += coef * (((j == cstar) ? 1.0f : 0.0f) - p);
        float uu = u_old[k] * 0.999f;
        m[k] = 0.9f * m_old[k] + 0.1f * g;
        v[k] = 0.999f * v_old[k] + 0.001f * g * g;
        const float mh = m[k] * im1;
        const float vh = v[k] * im2;
        u[k] = uu - (0.1f * mh) / (sqrtf(vh) + 1e-8f);
      }
    }
  }

#pragma unroll
  for (int k = 0; k < 16; ++k) {
    const int j = lane + (k << 6);
    if (j < CC) ZU[(size_t)row * CC + j] = u[k];
  }
}

// ---------------------------------------------------------------------------
extern "C" void kernel_launch(void* const* d_in, const int* in_sizes, int n_in,
                              void* d_out, int out_size, void* d_ws,
                              size_t ws_size, hipStream_t stream) {
  const float* x = (const float*)d_in[0];
  const float* W = (const float*)d_in[1];
  const float* b = (const float*)d_in[2];
  float* z = (float*)d_out;  // z lives in d_out; overwritten with u at the end

  char* ws = (char*)d_ws;
  int* y_arr = (int*)ws;                              // 16 KB
  float* ltrg_arr = (float*)(ws + (16 << 10));        // 16 KB
  float* ptrg_arr = (float*)(ws + (32 << 10));        // 16 KB
  float* sorted = (float*)(ws + (48 << 10));          // 16 KB
  unsigned long long* slots =
      (unsigned long long*)(ws + (64 << 10));         // 4 KB (2 x 256)

  gemm_kernel<<<dim3(16, 64), 256, 0, stream>>>(x, W, b, z);
  stats_kernel<<<dim3(1024), 256, 0, stream>>>(z, y_arr, ltrg_arr, ptrg_arr);
  sort_kernel<<<dim3(1), 1024, 0, stream>>>(ptrg_arr, sorted);

  void* args[5] = {&z, &y_arr, &ltrg_arr, &sorted, &slots};
  hipLaunchCooperativeKernel((const void*)opt_kernel, dim3(256), dim3(1024),
                             args, 0u, stream);
}

// Round 4
// 1454.126 us; speedup vs baseline: 1.8799x; 1.8799x over previous
//
#include <hip/hip_runtime.h>

// Problem dims
#define BB 4096
#define DD 2048
#define CC 1000

// ---------------------------------------------------------------------------
// Common wave-level reductions.  Single shared definition used by both
// stats_kernel and opt_kernel so iteration-1 of the optimizer reproduces
// p_trg bitwise (the reference gets sign(0)=0 there).
// ---------------------------------------------------------------------------
__device__ __forceinline__ void wave_argmax(float& val, int& idx) {
#pragma unroll
  for (int off = 1; off < 64; off <<= 1) {
    float ov = __shfl_xor(val, off, 64);
    int oi = __shfl_xor(idx, off, 64);
    if (ov > val || (ov == val && oi < idx)) { val = ov; idx = oi; }
  }
}

__device__ __forceinline__ float wave_sum(float v) {
#pragma unroll
  for (int off = 1; off < 64; off <<= 1) v += __shfl_xor(v, off, 64);
  return v;
}

// ---------------------------------------------------------------------------
// GEMM: Z = X @ W + b   (fp32, 64x64 tile, BK=16, 4x4 per thread)
// ---------------------------------------------------------------------------
__global__ __launch_bounds__(256) void gemm_kernel(
    const float* __restrict__ X, const float* __restrict__ W,
    const float* __restrict__ Bv, float* __restrict__ Z) {
  __shared__ float sA[16][68];
  __shared__ float sB[16][68];
  const int tid = threadIdx.x;
  const int rowTile = blockIdx.y * 64;
  const int colTile = blockIdx.x * 64;
  const int tx = tid & 15, ty = tid >> 4;
  float acc[4][4] = {};

  const int aRow = tid >> 2;        // 0..63
  const int aK = (tid & 3) << 2;    // 0,4,8,12
  const int bK = tid >> 4;          // 0..15
  const int bC = (tid & 15) << 2;   // 0..60
  const bool fullCol = (colTile + 64) <= CC;

  for (int k0 = 0; k0 < DD; k0 += 16) {
    const float4 av = *(const float4*)&X[(size_t)(rowTile + aRow) * DD + k0 + aK];
    sA[aK + 0][aRow] = av.x;
    sA[aK + 1][aRow] = av.y;
    sA[aK + 2][aRow] = av.z;
    sA[aK + 3][aRow] = av.w;
    float4 bv;
    if (fullCol) {
      bv = *(const float4*)&W[(size_t)(k0 + bK) * CC + colTile + bC];
    } else {
      const int c0 = colTile + bC;
      bv.x = (c0 + 0 < CC) ? W[(size_t)(k0 + bK) * CC + c0 + 0] : 0.f;
      bv.y = (c0 + 1 < CC) ? W[(size_t)(k0 + bK) * CC + c0 + 1] : 0.f;
      bv.z = (c0 + 2 < CC) ? W[(size_t)(k0 + bK) * CC + c0 + 2] : 0.f;
      bv.w = (c0 + 3 < CC) ? W[(size_t)(k0 + bK) * CC + c0 + 3] : 0.f;
    }
    *(float4*)&sB[bK][bC] = bv;
    __syncthreads();
#pragma unroll
    for (int kk = 0; kk < 16; ++kk) {
      const float4 a4 = *(const float4*)&sA[kk][ty << 2];
      const float4 b4 = *(const float4*)&sB[kk][tx << 2];
      const float ar[4] = {a4.x, a4.y, a4.z, a4.w};
      const float br[4] = {b4.x, b4.y, b4.z, b4.w};
#pragma unroll
      for (int i = 0; i < 4; ++i)
#pragma unroll
        for (int j = 0; j < 4; ++j) acc[i][j] = fmaf(ar[i], br[j], acc[i][j]);
    }
    __syncthreads();
  }
#pragma unroll
  for (int i = 0; i < 4; ++i) {
    const int r = rowTile + (ty << 2) + i;
#pragma unroll
    for (int j = 0; j < 4; ++j) {
      const int c = colTile + (tx << 2) + j;
      if (c < CC) Z[(size_t)r * CC + c] = acc[i][j] + Bv[c];
    }
  }
}

// ---------------------------------------------------------------------------
// Per-row stats from z: y = argmax, l_trg, p_trg.
// One wave per row; lane l owns columns l + 64*k, k = 0..15.
// ---------------------------------------------------------------------------
__global__ __launch_bounds__(256) void stats_kernel(
    const float* __restrict__ Z, int* __restrict__ Y,
    float* __restrict__ Lt, float* __restrict__ Pt) {
  const int wave = threadIdx.x >> 6, lane = threadIdx.x & 63;
  const int row = blockIdx.x * 4 + wave;
  float uv[16];
#pragma unroll
  for (int k = 0; k < 16; ++k) {
    const int j = lane + (k << 6);
    uv[k] = (j < CC) ? Z[(size_t)row * CC + j] : -__builtin_inff();
  }
  float mx = uv[0];
  int ai = lane;
#pragma unroll
  for (int k = 1; k < 16; ++k) {
    const int j = lane + (k << 6);
    if (uv[k] > mx) { mx = uv[k]; ai = j; }
  }
  wave_argmax(mx, ai);
  float sum = 0.f;
#pragma unroll
  for (int k = 0; k < 16; ++k) sum += expf(uv[k] - mx);
  sum = wave_sum(sum);
  if (lane == 0) {
    const float lse = mx + logf(sum);
    const float lorg = lse - mx;  // == lse - z[y]
    const float latr = (floorf(lorg / 6.0f) + 0.5f) * 6.0f;
    const float lt =
        lorg - 6.0f * sinf(3.14159265358979323846f *
                           (1.0f - 2.0f * (lorg - latr) / 6.0f));
    Y[row] = ai;
    Lt[row] = lt;
    Pt[row] = 1.0f / sum;  // max softmax = exp(max - lse) = 1/sum
  }
}

// ---------------------------------------------------------------------------
// Bitonic sort of p_trg (4096) in LDS, single block.
// ---------------------------------------------------------------------------
__global__ __launch_bounds__(1024) void sort_kernel(
    const float* __restrict__ P, float* __restrict__ Out) {
  __shared__ float s[4096];
  const int tid = threadIdx.x;
  for (int i = tid; i < 4096; i += 1024) s[i] = P[i];
  __syncthreads();
  for (int k = 2; k <= 4096; k <<= 1) {
    for (int j = k >> 1; j > 0; j >>= 1) {
      for (int i = tid; i < 4096; i += 1024) {
        const int ixj = i ^ j;
        if (ixj > i) {
          const float a = s[i], b = s[ixj];
          const bool up = ((i & k) == 0);
          if (up ? (a > b) : (a < b)) { s[i] = b; s[ixj] = a; }
        }
      }
      __syncthreads();
    }
  }
  for (int i = tid; i < 4096; i += 1024) Out[i] = s[i];
}

// ---------------------------------------------------------------------------
// Cooperative optimizer: 256 blocks x 1024 threads, 1 block/CU.
// One wave per row; u,m,v,e live in registers for all 100 iterations.
// __launch_bounds__(1024, 1): VGPR cap 128 (NOT 64) — the (1024,4) bound in
// earlier rounds capped at 64 VGPRs and spilled the entire state to scratch.
//
// Sync protocol (RELAXED atomics; all cross-block data packed in one 64-bit
// slot word {pmax:32 | epoch:8 | row,col:22}, parity double-buffered; the
// epoch tag orders the protocol — a slot of epoch t is only overwritten at
// t+2, after every block has finished reading t).
//
// Latency hiding (no extra state): only a block's candidate wave (block-max
// pmax row) can be the global winner r*.  All waves redundantly reduce the
// 16 LDS candidates; the 15 non-candidate waves apply their final term1-only
// update immediately (overlapping the poll); the candidate wave defers its
// single update until after the poll and applies the exact combined
// gradient.  Bitwise identical to the sequential path.
// ---------------------------------------------------------------------------
__global__ __launch_bounds__(1024, 1) void opt_kernel(
    float* __restrict__ ZU, const int* __restrict__ Yarr,
    const float* __restrict__ Ltrg, const float* __restrict__ Sorted,
    unsigned long long* __restrict__ Slots) {
  const int tid = threadIdx.x;
  const int wave = tid >> 6, lane = tid & 63;
  const int row = blockIdx.x * 16 + wave;

  __shared__ float s_sorted[4096];
  __shared__ float s_coarse[64];  // s_sorted[l*64] transposed: conflict-free
  __shared__ float s_cval[16];
  __shared__ int s_cidx[16];
  __shared__ float s_coef;
  __shared__ int s_rc;  // rstar<<10 | cstar

  for (int i = tid; i < 4096; i += 1024) s_sorted[i] = Sorted[i];
  if (tid < 64) s_coarse[tid] = Sorted[tid << 6];

  float u[16], m[16], v[16], e[16];
#pragma unroll
  for (int k = 0; k < 16; ++k) {
    const int j = lane + (k << 6);
    u[k] = (j < CC) ? ZU[(size_t)row * CC + j] : -__builtin_inff();
    m[k] = 0.f;
    v[k] = 0.f;
  }
  const int y = Yarr[row];
  const float ltrg = Ltrg[row];
  const int ky = y >> 6, ly = y & 63;

  float pb1 = 1.0f, pb2 = 1.0f;
  __syncthreads();

#pragma unroll 1
  for (int t = 1; t <= 100; ++t) {
    pb1 *= 0.9f;
    pb2 *= 0.999f;
    const float im1 = 1.0f / (1.0f - pb1);
    const float im2 = 1.0f / (1.0f - pb2);

    // ---- Phase A: row stats (same arithmetic as stats_kernel) ----
    float mx = u[0];
    int ai = lane;
#pragma unroll
    for (int k = 1; k < 16; ++k) {
      const int j = lane + (k << 6);
      if (u[k] > mx) { mx = u[k]; ai = j; }
    }
    wave_argmax(mx, ai);
    float sum = 0.f;
#pragma unroll
    for (int k = 0; k < 16; ++k) {
      e[k] = expf(u[k] - mx);
      sum += e[k];
    }
    sum = wave_sum(sum);
    const float lse = mx + logf(sum);
    float uyl = 0.f;
#pragma unroll
    for (int k = 0; k < 16; ++k) uyl = (k == ky) ? u[k] : uyl;
    const float uy = __shfl(uyl, ly, 64);
    const float ce = lse - uy;
    const float pmax = 1.0f / sum;  // row max softmax
    const float a = (ce > ltrg) ? 1.0f : ((ce < ltrg) ? -1.0f : 0.0f);

    if (lane == 0) {
      s_cval[wave] = pmax;
      s_cidx[wave] = (row << 10) | ai;
    }
    __syncthreads();  // B1

    // ---- every wave: redundant block-reduce of the 16 candidates ----
    float bv = s_cval[0];
    int bi = s_cidx[0];
#pragma unroll
    for (int w = 1; w < 16; ++w) {
      const float ov = s_cval[w];
      const int oi = s_cidx[w];
      if (ov > bv || (ov == bv && oi < bi)) { bv = ov; bi = oi; }
    }
    const int candw = (bi >> 10) & 15;  // wave index of block candidate
    const bool iscand = (wave == candw);

    unsigned long long* slot_buf = &Slots[(t & 1) * 256];
    if (tid == 0) {
      const unsigned long long pack =
          ((unsigned long long)__float_as_uint(bv) << 32) |
          (unsigned)((t << 24) | bi);
      __hip_atomic_store(&slot_buf[blockIdx.x], pack, __ATOMIC_RELAXED,
                         __HIP_MEMORY_SCOPE_AGENT);
    }

    // exact AdamW step for this wave's row; term2 only when win
    auto adam_update = [&](bool with_t2, float coef, int cstar) {
#pragma unroll
      for (int k = 0; k < 16; ++k) {
        const int j = lane + (k << 6);
        const float p = e[k] * pmax;  // softmax(u)[j] = exp(u-mx)/sum
        float g = a * (p - ((j == y) ? 1.0f : 0.0f));
        if (with_t2) g += coef * (((j == cstar) ? 1.0f : 0.0f) - p);
        u[k] *= 0.999f;  // 1 - LR*WD
        m[k] = 0.9f * m[k] + 0.1f * g;
        v[k] = 0.999f * v[k] + 0.001f * g * g;
        const float mh = m[k] * im1;
        const float vh = v[k] * im2;
        u[k] -= (0.1f * mh) / (sqrtf(vh) + 1e-8f);
      }
    };

    // ---- non-candidate waves: final update now (overlaps the poll) ----
    if (!iscand && wave != 0) adam_update(false, 0.f, 0);

    // ---- wave 0: (own update if non-candidate), then poll + reduce ----
    if (wave == 0) {
      if (!iscand) adam_update(false, 0.f, 0);
      unsigned long long pv[4];
      unsigned fresh = 0u;
      while (fresh != 0xFu) {
#pragma unroll
        for (int q = 0; q < 4; ++q) {
          if (!(fresh & (1u << q))) {
            const unsigned long long p = __hip_atomic_load(
                &slot_buf[lane + (q << 6)], __ATOMIC_RELAXED,
                __HIP_MEMORY_SCOPE_AGENT);
            if ((unsigned)((p >> 24) & 0xFFu) == (unsigned)t) {
              pv[q] = p;
              fresh |= 1u << q;
            }
          }
        }
        if (fresh != 0xFu) __builtin_amdgcn_s_sleep(1);
      }
      float gv = -1.0f;
      int gi = 0x7fffffff;
#pragma unroll
      for (int q = 0; q < 4; ++q) {
        const float ov = __uint_as_float((unsigned)(pv[q] >> 32));
        const int oi = (int)(pv[q] & 0x3FFFFFu);
        if (ov > gv || (ov == gv && oi < gi)) { gv = ov; gi = oi; }
      }
      wave_argmax(gv, gi);
      const float ss = gv;
      // rank queries on sorted p_trg: S = #(p_trg < ss) - #(p_trg > ss)
      const float v1 = s_coarse[lane];
      const int c1 = __popcll(__ballot(v1 < ss));
      int nlt = 0;
      if (c1 > 0) {
        const float v2 = s_sorted[((c1 - 1) << 6) + lane];
        nlt = ((c1 - 1) << 6) + __popcll(__ballot(v2 < ss));
      }
      const int c2 = __popcll(__ballot(v1 <= ss));
      int nle = 0;
      if (c2 > 0) {
        const float v3 = s_sorted[((c2 - 1) << 6) + lane];
        nle = ((c2 - 1) << 6) + __popcll(__ballot(v3 <= ss));
      }
      const int S = nlt - (4096 - nle);
      if (lane == 0) {
        s_coef = 5.0f * (float)S * ss;  // BETA * S * M
        s_rc = gi;
      }
    }
    __syncthreads();  // B2

    // ---- candidate wave: deferred update with exact combined gradient ----
    if (iscand) {
      const int rc = s_rc;
      const bool win = ((rc >> 10) == row);
      adam_update(win, s_coef, rc & 1023);
    }
  }

#pragma unroll
  for (int k = 0; k < 16; ++k) {
    const int j = lane + (k << 6);
    if (j < CC) ZU[(size_t)row * CC + j] = u[k];
  }
}

// ---------------------------------------------------------------------------
extern "C" void kernel_launch(void* const* d_in, const int* in_sizes, int n_in,
                              void* d_out, int out_size, void* d_ws,
                              size_t ws_size, hipStream_t stream) {
  const float* x = (const float*)d_in[0];
  const float* W = (const float*)d_in[1];
  const float* b = (const float*)d_in[2];
  float* z = (float*)d_out;  // z lives in d_out; overwritten with u at the end

  char* ws = (char*)d_ws;
  int* y_arr = (int*)ws;                              // 16 KB
  float* ltrg_arr = (float*)(ws + (16 << 10));        // 16 KB
  float* ptrg_arr = (float*)(ws + (32 << 10));        // 16 KB
  float* sorted = (float*)(ws + (48 << 10));          // 16 KB
  unsigned long long* slots =
      (unsigned long long*)(ws + (64 << 10));         // 4 KB (2 x 256)

  gemm_kernel<<<dim3(16, 64), 256, 0, stream>>>(x, W, b, z);
  stats_kernel<<<dim3(1024), 256, 0, stream>>>(z, y_arr, ltrg_arr, ptrg_arr);
  sort_kernel<<<dim3(1), 1024, 0, stream>>>(ptrg_arr, sorted);

  void* args[5] = {&z, &y_arr, &ltrg_arr, &sorted, &slots};
  hipLaunchCooperativeKernel((const void*)opt_kernel, dim3(256), dim3(1024),
                             args, 0u, stream);
}

// Round 7
// 1377.654 us; speedup vs baseline: 1.9843x; 1.0555x over previous
//
#include <hip/hip_runtime.h>

// Problem dims
#define BB 4096
#define DD 2048
#define CC 1000

// R6 post-mortem: 512-block cooperative launch FAILS validation (absmax
// identical to R5 with different math => opt never ran).  Stay at the proven
// 256 blocks x 1024 threads.  All math is the R4-proven precise form.
// ---------------------------------------------------------------------------
__device__ __forceinline__ void wave_argmax(float& val, int& idx) {
#pragma unroll
  for (int off = 1; off < 64; off <<= 1) {
    float ov = __shfl_xor(val, off, 64);
    int oi = __shfl_xor(idx, off, 64);
    if (ov > val || (ov == val && oi < idx)) { val = ov; idx = oi; }
  }
}

__device__ __forceinline__ float wave_sum(float v) {
#pragma unroll
  for (int off = 1; off < 64; off <<= 1) v += __shfl_xor(v, off, 64);
  return v;
}

// ---------------------------------------------------------------------------
// GEMM: Z = X @ W + b   (fp32, 64x64 tile, BK=16, 4x4 per thread)
// Do NOT alter accumulation order: z bits feed the sign-gated trajectory.
// ---------------------------------------------------------------------------
__global__ __launch_bounds__(256) void gemm_kernel(
    const float* __restrict__ X, const float* __restrict__ W,
    const float* __restrict__ Bv, float* __restrict__ Z) {
  __shared__ float sA[16][68];
  __shared__ float sB[16][68];
  const int tid = threadIdx.x;
  const int rowTile = blockIdx.y * 64;
  const int colTile = blockIdx.x * 64;
  const int tx = tid & 15, ty = tid >> 4;
  float acc[4][4] = {};

  const int aRow = tid >> 2;        // 0..63
  const int aK = (tid & 3) << 2;    // 0,4,8,12
  const int bK = tid >> 4;          // 0..15
  const int bC = (tid & 15) << 2;   // 0..60
  const bool fullCol = (colTile + 64) <= CC;

  for (int k0 = 0; k0 < DD; k0 += 16) {
    const float4 av = *(const float4*)&X[(size_t)(rowTile + aRow) * DD + k0 + aK];
    sA[aK + 0][aRow] = av.x;
    sA[aK + 1][aRow] = av.y;
    sA[aK + 2][aRow] = av.z;
    sA[aK + 3][aRow] = av.w;
    float4 bv;
    if (fullCol) {
      bv = *(const float4*)&W[(size_t)(k0 + bK) * CC + colTile + bC];
    } else {
      const int c0 = colTile + bC;
      bv.x = (c0 + 0 < CC) ? W[(size_t)(k0 + bK) * CC + c0 + 0] : 0.f;
      bv.y = (c0 + 1 < CC) ? W[(size_t)(k0 + bK) * CC + c0 + 1] : 0.f;
      bv.z = (c0 + 2 < CC) ? W[(size_t)(k0 + bK) * CC + c0 + 2] : 0.f;
      bv.w = (c0 + 3 < CC) ? W[(size_t)(k0 + bK) * CC + c0 + 3] : 0.f;
    }
    *(float4*)&sB[bK][bC] = bv;
    __syncthreads();
#pragma unroll
    for (int kk = 0; kk < 16; ++kk) {
      const float4 a4 = *(const float4*)&sA[kk][ty << 2];
      const float4 b4 = *(const float4*)&sB[kk][tx << 2];
      const float ar[4] = {a4.x, a4.y, a4.z, a4.w};
      const float br[4] = {b4.x, b4.y, b4.z, b4.w};
#pragma unroll
      for (int i = 0; i < 4; ++i)
#pragma unroll
        for (int j = 0; j < 4; ++j) acc[i][j] = fmaf(ar[i], br[j], acc[i][j]);
    }
    __syncthreads();
  }
#pragma unroll
  for (int i = 0; i < 4; ++i) {
    const int r = rowTile + (ty << 2) + i;
#pragma unroll
    for (int j = 0; j < 4; ++j) {
      const int c = colTile + (tx << 2) + j;
      if (c < CC) Z[(size_t)r * CC + c] = acc[i][j] + Bv[c];
    }
  }
}

// ---------------------------------------------------------------------------
// Per-row stats from z: y = argmax, l_trg, p_trg.
// One wave per row; lane l owns columns l + 64*k, k = 0..15.
// ---------------------------------------------------------------------------
__global__ __launch_bounds__(256) void stats_kernel(
    const float* __restrict__ Z, int* __restrict__ Y,
    float* __restrict__ Lt, float* __restrict__ Pt) {
  const int wave = threadIdx.x >> 6, lane = threadIdx.x & 63;
  const int row = blockIdx.x * 4 + wave;
  float uv[16];
#pragma unroll
  for (int k = 0; k < 16; ++k) {
    const int j = lane + (k << 6);
    uv[k] = (j < CC) ? Z[(size_t)row * CC + j] : -__builtin_inff();
  }
  float mx = uv[0];
  int ai = lane;
#pragma unroll
  for (int k = 1; k < 16; ++k) {
    const int j = lane + (k << 6);
    if (uv[k] > mx) { mx = uv[k]; ai = j; }
  }
  wave_argmax(mx, ai);
  float sum = 0.f;
#pragma unroll
  for (int k = 0; k < 16; ++k) sum += expf(uv[k] - mx);
  sum = wave_sum(sum);
  if (lane == 0) {
    const float lse = mx + logf(sum);
    const float lorg = lse - mx;  // == lse - z[y], same expr tree as opt's ce
    const float latr = (floorf(lorg / 6.0f) + 0.5f) * 6.0f;
    const float lt =
        lorg - 6.0f * sinf(3.14159265358979323846f *
                           (1.0f - 2.0f * (lorg - latr) / 6.0f));
    Y[row] = ai;
    Lt[row] = lt;
    Pt[row] = 1.0f / sum;  // max softmax = exp(max - lse) = 1/sum
  }
}

// ---------------------------------------------------------------------------
// Bitonic sort of p_trg (4096) in LDS, single block.
// ---------------------------------------------------------------------------
__global__ __launch_bounds__(1024) void sort_kernel(
    const float* __restrict__ P, float* __restrict__ Out) {
  __shared__ float s[4096];
  const int tid = threadIdx.x;
  for (int i = tid; i < 4096; i += 1024) s[i] = P[i];
  __syncthreads();
  for (int k = 2; k <= 4096; k <<= 1) {
    for (int j = k >> 1; j > 0; j >>= 1) {
      for (int i = tid; i < 4096; i += 1024) {
        const int ixj = i ^ j;
        if (ixj > i) {
          const float a = s[i], b = s[ixj];
          const bool up = ((i & k) == 0);
          if (up ? (a > b) : (a < b)) { s[i] = b; s[ixj] = a; }
        }
      }
      __syncthreads();
    }
  }
  for (int i = tid; i < 4096; i += 1024) Out[i] = s[i];
}

// ---------------------------------------------------------------------------
// Cooperative optimizer: 256 blocks x 1024 threads (R4-proven residency).
// One wave per row; u,m,v,e live in registers for all 100 iterations.
//
// R7: the per-iteration __syncthreads() pair is replaced by a BARRIER-FREE
// LDS pipeline (monotone parity arrival counters + done flags, workgroup-
// scope LDS atomics).  The 15 non-candidate waves never wait for wave 0's
// global poll — they finish their term1-only update and run ahead into
// iteration t+1's phase A; only the candidate wave consumes the poll result
// (via s_done) on the critical path.  Per-row arithmetic order is unchanged
// => trajectory bitwise identical to R4 (absmax 0.140625).
//
// Safety sketch: wave x's arrival(t+2) requires x passed arrive-spin(t+1),
// which requires ALL waves arrived(t+1); a candidate-of-t wave arrives(t+1)
// only after its deferred update (which read s_coef/s_rc of t) — so parity
// buffers (s_cval/s_cidx/s_coef/s_rc) are never overwritten while readable.
// Globally: block X stores slot(t+2) only after X's poll(t+1) completed,
// which requires every block stored slot(t+1), which requires every block's
// poll(t) completed — slot parity reuse is hang/tear-free.
// ---------------------------------------------------------------------------
__global__ __launch_bounds__(1024, 1) void opt_kernel(
    float* __restrict__ ZU, const int* __restrict__ Yarr,
    const float* __restrict__ Ltrg, const float* __restrict__ Sorted,
    unsigned long long* __restrict__ Slots) {
  const int tid = threadIdx.x;
  const int wave = tid >> 6, lane = tid & 63;
  const int row = blockIdx.x * 16 + wave;

  __shared__ float s_sorted[4096];
  __shared__ float s_coarse[64];  // s_sorted[l*64] transposed: conflict-free
  __shared__ float s_cval[2][16];
  __shared__ int s_cidx[2][16];
  __shared__ float s_coef[2];
  __shared__ int s_rc[2];     // rstar<<10 | cstar
  __shared__ int s_arrive[2];  // monotone arrival counters (per parity)
  __shared__ int s_done[2];    // monotone poll-done epoch (per parity)

  for (int i = tid; i < 4096; i += 1024) s_sorted[i] = Sorted[i];
  if (tid < 64) s_coarse[tid] = Sorted[tid << 6];
  if (tid == 0) {
    s_arrive[0] = 0;
    s_arrive[1] = 0;
    s_done[0] = 0;
    s_done[1] = 0;
  }

  float u[16], m[16], v[16], e[16];
#pragma unroll
  for (int k = 0; k < 16; ++k) {
    const int j = lane + (k << 6);
    u[k] = (j < CC) ? ZU[(size_t)row * CC + j] : -__builtin_inff();
    m[k] = 0.f;
    v[k] = 0.f;
  }
  const int y = Yarr[row];
  const float ltrg = Ltrg[row];
  const int ky = y >> 6, ly = y & 63;

  float pb1 = 1.0f, pb2 = 1.0f;
  __syncthreads();  // covers s_sorted/s_coarse/counter init only

#pragma unroll 1
  for (int t = 1; t <= 100; ++t) {
    const int p = t & 1;
    pb1 *= 0.9f;
    pb2 *= 0.999f;
    const float im1 = 1.0f / (1.0f - pb1);
    const float im2 = 1.0f / (1.0f - pb2);

    // ---- Phase A: row stats (same arithmetic as stats_kernel) ----
    float mx = u[0];
    int ai = lane;
#pragma unroll
    for (int k = 1; k < 16; ++k) {
      const int j = lane + (k << 6);
      if (u[k] > mx) { mx = u[k]; ai = j; }
    }
    wave_argmax(mx, ai);
    float sum = 0.f;
#pragma unroll
    for (int k = 0; k < 16; ++k) {
      e[k] = expf(u[k] - mx);
      sum += e[k];
    }
    sum = wave_sum(sum);
    const float lse = mx + logf(sum);
    float uyl = 0.f;
#pragma unroll
    for (int k = 0; k < 16; ++k) uyl = (k == ky) ? u[k] : uyl;
    const float uy = __shfl(uyl, ly, 64);
    const float ce = lse - uy;
    const float pmax = 1.0f / sum;  // row max softmax
    const float a = (ce > ltrg) ? 1.0f : ((ce < ltrg) ? -1.0f : 0.0f);

    // ---- publish candidate + arrive (release), then spin (acquire) ----
    if (lane == 0) {
      s_cval[p][wave] = pmax;
      s_cidx[p][wave] = (row << 10) | ai;
      __hip_atomic_fetch_add(&s_arrive[p], 1, __ATOMIC_RELEASE,
                             __HIP_MEMORY_SCOPE_WORKGROUP);
    }
    const int target = 16 * ((t >> 1) + (t & 1));  // monotone per-parity
    while (__hip_atomic_load(&s_arrive[p], __ATOMIC_ACQUIRE,
                             __HIP_MEMORY_SCOPE_WORKGROUP) < target) {
    }

    // ---- every wave: redundant block-reduce of the 16 candidates ----
    float bv = s_cval[p][0];
    int bi = s_cidx[p][0];
#pragma unroll
    for (int w = 1; w < 16; ++w) {
      const float ov = s_cval[p][w];
      const int oi = s_cidx[p][w];
      if (ov > bv || (ov == bv && oi < bi)) { bv = ov; bi = oi; }
    }
    const int candw = (bi >> 10) & 15;  // wave index of block candidate
    const bool iscand = (wave == candw);

    unsigned long long* slot_buf = &Slots[p * 256];
    if (tid == 0) {
      const unsigned long long pack =
          ((unsigned long long)__float_as_uint(bv) << 32) |
          (unsigned)((t << 24) | bi);
      __hip_atomic_store(&slot_buf[blockIdx.x], pack, __ATOMIC_RELAXED,
                         __HIP_MEMORY_SCOPE_AGENT);
    }

    // exact AdamW step for this wave's row; term2 only when win
    auto adam_update = [&](bool with_t2, float coef, int cstar) {
#pragma unroll
      for (int k = 0; k < 16; ++k) {
        const int j = lane + (k << 6);
        const float p2 = e[k] * pmax;  // softmax(u)[j]
        float g = a * (p2 - ((j == y) ? 1.0f : 0.0f));
        if (with_t2) g += coef * (((j == cstar) ? 1.0f : 0.0f) - p2);
        u[k] *= 0.999f;  // 1 - LR*WD
        m[k] = 0.9f * m[k] + 0.1f * g;
        v[k] = 0.999f * v[k] + 0.001f * g * g;
        const float mh = m[k] * im1;
        const float vh = v[k] * im2;
        u[k] -= (0.1f * mh) / (sqrtf(vh) + 1e-8f);
      }
    };

    // ---- non-candidate waves: update now, then run ahead (no barrier) ----
    if (!iscand && wave != 0) adam_update(false, 0.f, 0);

    // ---- wave 0: (own update), then poll + reduce + publish ----
    if (wave == 0) {
      if (!iscand) adam_update(false, 0.f, 0);
      unsigned long long pv[4];
      unsigned fresh = 0u;
      while (fresh != 0xFu) {
#pragma unroll
        for (int q = 0; q < 4; ++q) {
          if (!(fresh & (1u << q))) {
            const unsigned long long pk = __hip_atomic_load(
                &slot_buf[lane + (q << 6)], __ATOMIC_RELAXED,
                __HIP_MEMORY_SCOPE_AGENT);
            if ((unsigned)((pk >> 24) & 0xFFu) == (unsigned)t) {
              pv[q] = pk;
              fresh |= 1u << q;
            }
          }
        }
        if (fresh != 0xFu) __builtin_amdgcn_s_sleep(1);
      }
      float gv = -1.0f;
      int gi = 0x7fffffff;
#pragma unroll
      for (int q = 0; q < 4; ++q) {
        const float ov = __uint_as_float((unsigned)(pv[q] >> 32));
        const int oi = (int)(pv[q] & 0x3FFFFFu);
        if (ov > gv || (ov == gv && oi < gi)) { gv = ov; gi = oi; }
      }
      wave_argmax(gv, gi);
      const float ss = gv;
      // rank queries on sorted p_trg: S = #(p_trg < ss) - #(p_trg > ss)
      const float v1 = s_coarse[lane];
      const int c1 = __popcll(__ballot(v1 < ss));
      int nlt = 0;
      if (c1 > 0) {
        const float v2 = s_sorted[((c1 - 1) << 6) + lane];
        nlt = ((c1 - 1) << 6) + __popcll(__ballot(v2 < ss));
      }
      const int c2 = __popcll(__ballot(v1 <= ss));
      int nle = 0;
      if (c2 > 0) {
        const float v3 = s_sorted[((c2 - 1) << 6) + lane];
        nle = ((c2 - 1) << 6) + __popcll(__ballot(v3 <= ss));
      }
      const int S = nlt - (4096 - nle);
      if (lane == 0) {
        s_coef[p] = 5.0f * (float)S * ss;  // BETA * S * M
        s_rc[p] = gi;
        __hip_atomic_store(&s_done[p], t, __ATOMIC_RELEASE,
                           __HIP_MEMORY_SCOPE_WORKGROUP);
      }
    }

    // ---- candidate wave: wait for poll result, deferred exact update ----
    if (iscand) {
      while (__hip_atomic_load(&s_done[p], __ATOMIC_ACQUIRE,
                               __HIP_MEMORY_SCOPE_WORKGROUP) < t) {
      }
      const int rc = s_rc[p];
      const bool win = ((rc >> 10) == row);
      adam_update(win, s_coef[p], rc & 1023);
    }
  }

#pragma unroll
  for (int k = 0; k < 16; ++k) {
    const int j = lane + (k << 6);
    if (j < CC) ZU[(size_t)row * CC + j] = u[k];
  }
}

// ---------------------------------------------------------------------------
extern "C" void kernel_launch(void* const* d_in, const int* in_sizes, int n_in,
                              void* d_out, int out_size, void* d_ws,
                              size_t ws_size, hipStream_t stream) {
  const float* x = (const float*)d_in[0];
  const float* W = (const float*)d_in[1];
  const float* b = (const float*)d_in[2];
  float* z = (float*)d_out;  // z lives in d_out; overwritten with u at the end

  char* ws = (char*)d_ws;
  int* y_arr = (int*)ws;                              // 16 KB
  float* ltrg_arr = (float*)(ws + (16 << 10));        // 16 KB
  float* ptrg_arr = (float*)(ws + (32 << 10));        // 16 KB
  float* sorted = (float*)(ws + (48 << 10));          // 16 KB
  unsigned long long* slots =
      (unsigned long long*)(ws + (64 << 10));         // 4 KB (2 x 256)

  gemm_kernel<<<dim3(16, 64), 256, 0, stream>>>(x, W, b, z);
  stats_kernel<<<dim3(1024), 256, 0, stream>>>(z, y_arr, ltrg_arr, ptrg_arr);
  sort_kernel<<<dim3(1), 1024, 0, stream>>>(ptrg_arr, sorted);

  void* args[5] = {&z, &y_arr, &ltrg_arr, &sorted, &slots};
  hipLaunchCooperativeKernel((const void*)opt_kernel, dim3(256), dim3(1024),
                             args, 0u, stream);
}

// Round 8
// 1124.311 us; speedup vs baseline: 2.4314x; 1.2253x over previous
//
#include <hip/hip_runtime.h>

// Problem dims
#define BB 4096
#define DD 2048
#define CC 1000

// ---------------------------------------------------------------------------
// R8: R7's proven shell (256x1024 barrier-free pipeline, absmax 0.140625)
// + fast transcendentals (v_exp/v_rcp/v_sqrt) — the numeric lever R5 never
// actually tested (R5/R6 absmax were bit-identical => the 512-block launch
// failed, not the math).  stats and opt share IDENTICAL expression trees so
// the t=1 winner-row tie (sign(0)=0) is still bitwise-preserved.
// ---------------------------------------------------------------------------
__device__ __forceinline__ float fexp(float x) { return __expf(x); }
__device__ __forceinline__ float flog(float x) { return __logf(x); }
__device__ __forceinline__ float frcp(float x) {
  return __builtin_amdgcn_rcpf(x);
}
__device__ __forceinline__ float fsqrt(float x) {
  return __builtin_amdgcn_sqrtf(x);
}

__device__ __forceinline__ void wave_argmax(float& val, int& idx) {
#pragma unroll
  for (int off = 1; off < 64; off <<= 1) {
    float ov = __shfl_xor(val, off, 64);
    int oi = __shfl_xor(idx, off, 64);
    if (ov > val || (ov == val && oi < idx)) { val = ov; idx = oi; }
  }
}

__device__ __forceinline__ float wave_sum(float v) {
#pragma unroll
  for (int off = 1; off < 64; off <<= 1) v += __shfl_xor(v, off, 64);
  return v;
}

// ---------------------------------------------------------------------------
// GEMM: Z = X @ W + b   (fp32, 64x64 tile, BK=16, 4x4 per thread)
// Do NOT alter accumulation order: z bits feed floor()-bucketed l_trg.
// ---------------------------------------------------------------------------
__global__ __launch_bounds__(256) void gemm_kernel(
    const float* __restrict__ X, const float* __restrict__ W,
    const float* __restrict__ Bv, float* __restrict__ Z) {
  __shared__ float sA[16][68];
  __shared__ float sB[16][68];
  const int tid = threadIdx.x;
  const int rowTile = blockIdx.y * 64;
  const int colTile = blockIdx.x * 64;
  const int tx = tid & 15, ty = tid >> 4;
  float acc[4][4] = {};

  const int aRow = tid >> 2;        // 0..63
  const int aK = (tid & 3) << 2;    // 0,4,8,12
  const int bK = tid >> 4;          // 0..15
  const int bC = (tid & 15) << 2;   // 0..60
  const bool fullCol = (colTile + 64) <= CC;

  for (int k0 = 0; k0 < DD; k0 += 16) {
    const float4 av = *(const float4*)&X[(size_t)(rowTile + aRow) * DD + k0 + aK];
    sA[aK + 0][aRow] = av.x;
    sA[aK + 1][aRow] = av.y;
    sA[aK + 2][aRow] = av.z;
    sA[aK + 3][aRow] = av.w;
    float4 bv;
    if (fullCol) {
      bv = *(const float4*)&W[(size_t)(k0 + bK) * CC + colTile + bC];
    } else {
      const int c0 = colTile + bC;
      bv.x = (c0 + 0 < CC) ? W[(size_t)(k0 + bK) * CC + c0 + 0] : 0.f;
      bv.y = (c0 + 1 < CC) ? W[(size_t)(k0 + bK) * CC + c0 + 1] : 0.f;
      bv.z = (c0 + 2 < CC) ? W[(size_t)(k0 + bK) * CC + c0 + 2] : 0.f;
      bv.w = (c0 + 3 < CC) ? W[(size_t)(k0 + bK) * CC + c0 + 3] : 0.f;
    }
    *(float4*)&sB[bK][bC] = bv;
    __syncthreads();
#pragma unroll
    for (int kk = 0; kk < 16; ++kk) {
      const float4 a4 = *(const float4*)&sA[kk][ty << 2];
      const float4 b4 = *(const float4*)&sB[kk][tx << 2];
      const float ar[4] = {a4.x, a4.y, a4.z, a4.w};
      const float br[4] = {b4.x, b4.y, b4.z, b4.w};
#pragma unroll
      for (int i = 0; i < 4; ++i)
#pragma unroll
        for (int j = 0; j < 4; ++j) acc[i][j] = fmaf(ar[i], br[j], acc[i][j]);
    }
    __syncthreads();
  }
#pragma unroll
  for (int i = 0; i < 4; ++i) {
    const int r = rowTile + (ty << 2) + i;
#pragma unroll
    for (int j = 0; j < 4; ++j) {
      const int c = colTile + (tx << 2) + j;
      if (c < CC) Z[(size_t)r * CC + c] = acc[i][j] + Bv[c];
    }
  }
}

// ---------------------------------------------------------------------------
// Per-row stats from z: y = argmax, l_trg, p_trg.
// One wave per row; lane l owns columns l + 64*k, k = 0..15.
// Phase-A math MUST match opt_kernel's bitwise (fexp/flog/frcp, same trees).
// ---------------------------------------------------------------------------
__global__ __launch_bounds__(256) void stats_kernel(
    const float* __restrict__ Z, int* __restrict__ Y,
    float* __restrict__ Lt, float* __restrict__ Pt) {
  const int wave = threadIdx.x >> 6, lane = threadIdx.x & 63;
  const int row = blockIdx.x * 4 + wave;
  float uv[16];
#pragma unroll
  for (int k = 0; k < 16; ++k) {
    const int j = lane + (k << 6);
    uv[k] = (j < CC) ? Z[(size_t)row * CC + j] : -__builtin_inff();
  }
  float mx = uv[0];
  int ai = lane;
#pragma unroll
  for (int k = 1; k < 16; ++k) {
    const int j = lane + (k << 6);
    if (uv[k] > mx) { mx = uv[k]; ai = j; }
  }
  wave_argmax(mx, ai);
  float sum = 0.f;
#pragma unroll
  for (int k = 0; k < 16; ++k) sum += fexp(uv[k] - mx);
  sum = wave_sum(sum);
  if (lane == 0) {
    const float lse = mx + flog(sum);
    const float lorg = lse - mx;  // == lse - z[y], same expr tree as opt's ce
    const float latr = (floorf(lorg / 6.0f) + 0.5f) * 6.0f;
    const float lt =
        lorg - 6.0f * sinf(3.14159265358979323846f *
                           (1.0f - 2.0f * (lorg - latr) / 6.0f));
    Y[row] = ai;
    Lt[row] = lt;
    Pt[row] = frcp(sum);  // max softmax = exp(max - lse) = 1/sum
  }
}

// ---------------------------------------------------------------------------
// Bitonic sort of p_trg (4096) in LDS, single block.
// ---------------------------------------------------------------------------
__global__ __launch_bounds__(1024) void sort_kernel(
    const float* __restrict__ P, float* __restrict__ Out) {
  __shared__ float s[4096];
  const int tid = threadIdx.x;
  for (int i = tid; i < 4096; i += 1024) s[i] = P[i];
  __syncthreads();
  for (int k = 2; k <= 4096; k <<= 1) {
    for (int j = k >> 1; j > 0; j >>= 1) {
      for (int i = tid; i < 4096; i += 1024) {
        const int ixj = i ^ j;
        if (ixj > i) {
          const float a = s[i], b = s[ixj];
          const bool up = ((i & k) == 0);
          if (up ? (a > b) : (a < b)) { s[i] = b; s[ixj] = a; }
        }
      }
      __syncthreads();
    }
  }
  for (int i = tid; i < 4096; i += 1024) Out[i] = s[i];
}

// ---------------------------------------------------------------------------
// Cooperative optimizer: 256 blocks x 1024 threads (R4/R7-proven residency).
// One wave per row; u,m,v,e live in registers for all 100 iterations.
// Barrier-free LDS pipeline (R7): monotone parity arrival counters + done
// flags; non-candidate waves run ahead into t+1; only the candidate wave
// consumes the grid-poll result on the critical path.
//
// Safety sketch: wave x's arrival(t+2) requires x passed arrive-spin(t+1),
// which requires ALL waves arrived(t+1); a candidate-of-t wave arrives(t+1)
// only after its deferred update (which read s_coef/s_rc of t) — so parity
// buffers are never overwritten while readable.  Globally: block X stores
// slot(t+2) only after X's poll(t+1), which requires every block's slot(t+1),
// which requires every block's poll(t) — slot parity reuse is hang/tear-free.
// ---------------------------------------------------------------------------
__global__ __launch_bounds__(1024, 1) void opt_kernel(
    float* __restrict__ ZU, const int* __restrict__ Yarr,
    const float* __restrict__ Ltrg, const float* __restrict__ Sorted,
    unsigned long long* __restrict__ Slots) {
  const int tid = threadIdx.x;
  const int wave = tid >> 6, lane = tid & 63;
  const int row = blockIdx.x * 16 + wave;

  __shared__ float s_sorted[4096];
  __shared__ float s_coarse[64];  // s_sorted[l*64] transposed: conflict-free
  __shared__ float s_cval[2][16];
  __shared__ int s_cidx[2][16];
  __shared__ float s_coef[2];
  __shared__ int s_rc[2];      // rstar<<10 | cstar
  __shared__ int s_arrive[2];  // monotone arrival counters (per parity)
  __shared__ int s_done[2];    // monotone poll-done epoch (per parity)

  for (int i = tid; i < 4096; i += 1024) s_sorted[i] = Sorted[i];
  if (tid < 64) s_coarse[tid] = Sorted[tid << 6];
  if (tid == 0) {
    s_arrive[0] = 0;
    s_arrive[1] = 0;
    s_done[0] = 0;
    s_done[1] = 0;
  }

  float u[16], m[16], v[16], e[16];
#pragma unroll
  for (int k = 0; k < 16; ++k) {
    const int j = lane + (k << 6);
    u[k] = (j < CC) ? ZU[(size_t)row * CC + j] : -__builtin_inff();
    m[k] = 0.f;
    v[k] = 0.f;
  }
  const int y = Yarr[row];
  const float ltrg = Ltrg[row];
  const int ky = y >> 6, ly = y & 63;

  float pb1 = 1.0f, pb2 = 1.0f;
  __syncthreads();  // covers s_sorted/s_coarse/counter init only

#pragma unroll 1
  for (int t = 1; t <= 100; ++t) {
    const int p = t & 1;
    pb1 *= 0.9f;
    pb2 *= 0.999f;
    const float im1 = frcp(1.0f - pb1);
    const float im2 = frcp(1.0f - pb2);

    // ---- Phase A: row stats (same expression trees as stats_kernel) ----
    float mx = u[0];
    int ai = lane;
#pragma unroll
    for (int k = 1; k < 16; ++k) {
      const int j = lane + (k << 6);
      if (u[k] > mx) { mx = u[k]; ai = j; }
    }
    wave_argmax(mx, ai);
    float sum = 0.f;
#pragma unroll
    for (int k = 0; k < 16; ++k) {
      e[k] = fexp(u[k] - mx);
      sum += e[k];
    }
    sum = wave_sum(sum);
    const float lse = mx + flog(sum);
    float uyl = 0.f;
#pragma unroll
    for (int k = 0; k < 16; ++k) uyl = (k == ky) ? u[k] : uyl;
    const float uy = __shfl(uyl, ly, 64);
    const float ce = lse - uy;
    const float pmax = frcp(sum);  // row max softmax
    const float a = (ce > ltrg) ? 1.0f : ((ce < ltrg) ? -1.0f : 0.0f);

    // ---- publish candidate + arrive (release), then spin (acquire) ----
    if (lane == 0) {
      s_cval[p][wave] = pmax;
      s_cidx[p][wave] = (row << 10) | ai;
      __hip_atomic_fetch_add(&s_arrive[p], 1, __ATOMIC_RELEASE,
                             __HIP_MEMORY_SCOPE_WORKGROUP);
    }
    const int target = 16 * ((t >> 1) + (t & 1));  // monotone per-parity
    while (__hip_atomic_load(&s_arrive[p], __ATOMIC_ACQUIRE,
                             __HIP_MEMORY_SCOPE_WORKGROUP) < target) {
    }

    // ---- every wave: redundant block-reduce of the 16 candidates ----
    float bv = s_cval[p][0];
    int bi = s_cidx[p][0];
#pragma unroll
    for (int w = 1; w < 16; ++w) {
      const float ov = s_cval[p][w];
      const int oi = s_cidx[p][w];
      if (ov > bv || (ov == bv && oi < bi)) { bv = ov; bi = oi; }
    }
    const int candw = (bi >> 10) & 15;  // wave index of block candidate
    const bool iscand = (wave == candw);

    unsigned long long* slot_buf = &Slots[p * 256];
    if (tid == 0) {
      const unsigned long long pack =
          ((unsigned long long)__float_as_uint(bv) << 32) |
          (unsigned)((t << 24) | bi);
      __hip_atomic_store(&slot_buf[blockIdx.x], pack, __ATOMIC_RELAXED,
                         __HIP_MEMORY_SCOPE_AGENT);
    }

    // exact AdamW step for this wave's row; term2 only when win
    auto adam_update = [&](bool with_t2, float coef, int cstar) {
#pragma unroll
      for (int k = 0; k < 16; ++k) {
        const int j = lane + (k << 6);
        const float p2 = e[k] * pmax;  // softmax(u)[j]
        float g = a * (p2 - ((j == y) ? 1.0f : 0.0f));
        if (with_t2) g += coef * (((j == cstar) ? 1.0f : 0.0f) - p2);
        u[k] *= 0.999f;  // 1 - LR*WD
        m[k] = 0.9f * m[k] + 0.1f * g;
        v[k] = 0.999f * v[k] + 0.001f * g * g;
        const float mh = m[k] * im1;
        const float vh = v[k] * im2;
        u[k] -= 0.1f * mh * frcp(fsqrt(vh) + 1e-8f);
      }
    };

    // ---- non-candidate waves: update now, then run ahead (no barrier) ----
    if (!iscand && wave != 0) adam_update(false, 0.f, 0);

    // ---- wave 0: (own update), then poll + reduce + publish ----
    if (wave == 0) {
      if (!iscand) adam_update(false, 0.f, 0);
      unsigned long long pv[4];
      unsigned fresh = 0u;
      while (fresh != 0xFu) {
#pragma unroll
        for (int q = 0; q < 4; ++q) {
          if (!(fresh & (1u << q))) {
            const unsigned long long pk = __hip_atomic_load(
                &slot_buf[lane + (q << 6)], __ATOMIC_RELAXED,
                __HIP_MEMORY_SCOPE_AGENT);
            if ((unsigned)((pk >> 24) & 0xFFu) == (unsigned)t) {
              pv[q] = pk;
              fresh |= 1u << q;
            }
          }
        }
        if (fresh != 0xFu) __builtin_amdgcn_s_sleep(1);
      }
      float gv = -1.0f;
      int gi = 0x7fffffff;
#pragma unroll
      for (int q = 0; q < 4; ++q) {
        const float ov = __uint_as_float((unsigned)(pv[q] >> 32));
        const int oi = (int)(pv[q] & 0x3FFFFFu);
        if (ov > gv || (ov == gv && oi < gi)) { gv = ov; gi = oi; }
      }
      wave_argmax(gv, gi);
      const float ss = gv;
      // rank queries on sorted p_trg: S = #(p_trg < ss) - #(p_trg > ss)
      const float v1 = s_coarse[lane];
      const int c1 = __popcll(__ballot(v1 < ss));
      int nlt = 0;
      if (c1 > 0) {
        const float v2 = s_sorted[((c1 - 1) << 6) + lane];
        nlt = ((c1 - 1) << 6) + __popcll(__ballot(v2 < ss));
      }
      const int c2 = __popcll(__ballot(v1 <= ss));
      int nle = 0;
      if (c2 > 0) {
        const float v3 = s_sorted[((c2 - 1) << 6) + lane];
        nle = ((c2 - 1) << 6) + __popcll(__ballot(v3 <= ss));
      }
      const int S = nlt - (4096 - nle);
      if (lane == 0) {
        s_coef[p] = 5.0f * (float)S * ss;  // BETA * S * M
        s_rc[p] = gi;
        __hip_atomic_store(&s_done[p], t, __ATOMIC_RELEASE,
                           __HIP_MEMORY_SCOPE_WORKGROUP);
      }
    }

    // ---- candidate wave: wait for poll result, deferred exact update ----
    if (iscand) {
      while (__hip_atomic_load(&s_done[p], __ATOMIC_ACQUIRE,
                               __HIP_MEMORY_SCOPE_WORKGROUP) < t) {
      }
      const int rc = s_rc[p];
      const bool win = ((rc >> 10) == row);
      adam_update(win, s_coef[p], rc & 1023);
    }
  }

#pragma unroll
  for (int k = 0; k < 16; ++k) {
    const int j = lane + (k << 6);
    if (j < CC) ZU[(size_t)row * CC + j] = u[k];
  }
}

// ---------------------------------------------------------------------------
extern "C" void kernel_launch(void* const* d_in, const int* in_sizes, int n_in,
                              void* d_out, int out_size, void* d_ws,
                              size_t ws_size, hipStream_t stream) {
  const float* x = (const float*)d_in[0];
  const float* W = (const float*)d_in[1];
  const float* b = (const float*)d_in[2];
  float* z = (float*)d_out;  // z lives in d_out; overwritten with u at the end

  char* ws = (char*)d_ws;
  int* y_arr = (int*)ws;                              // 16 KB
  float* ltrg_arr = (float*)(ws + (16 << 10));        // 16 KB
  float* ptrg_arr = (float*)(ws + (32 << 10));        // 16 KB
  float* sorted = (float*)(ws + (48 << 10));          // 16 KB
  unsigned long long* slots =
      (unsigned long long*)(ws + (64 << 10));         // 4 KB (2 x 256)

  gemm_kernel<<<dim3(16, 64), 256, 0, stream>>>(x, W, b, z);
  stats_kernel<<<dim3(1024), 256, 0, stream>>>(z, y_arr, ltrg_arr, ptrg_arr);
  sort_kernel<<<dim3(1), 1024, 0, stream>>>(ptrg_arr, sorted);

  void* args[5] = {&z, &y_arr, &ltrg_arr, &sorted, &slots};
  hipLaunchCooperativeKernel((const void*)opt_kernel, dim3(256), dim3(1024),
                             args, 0u, stream);
}

// Round 9
// 1014.635 us; speedup vs baseline: 2.6943x; 1.1081x over previous
//
#include <hip/hip_runtime.h>

// Problem dims
#define BB 4096
#define DD 2048
#define CC 1000

typedef short short8 __attribute__((ext_vector_type(8)));
typedef float f32x4 __attribute__((ext_vector_type(4)));

// RNE fp32 -> bf16 (inputs finite; no NaN handling needed)
__device__ __forceinline__ unsigned short f2bf(float x) {
  unsigned u = __float_as_uint(x);
  unsigned r = (u + 0x7FFFu + ((u >> 16) & 1u)) >> 16;
  return (unsigned short)r;
}
__device__ __forceinline__ float bf2f(unsigned short h) {
  return __uint_as_float(((unsigned)h) << 16);
}

__device__ __forceinline__ float fexp(float x) { return __expf(x); }
__device__ __forceinline__ float flog(float x) { return __logf(x); }
__device__ __forceinline__ float frcp(float x) {
  return __builtin_amdgcn_rcpf(x);
}
__device__ __forceinline__ float fsqrt(float x) {
  return __builtin_amdgcn_sqrtf(x);
}

__device__ __forceinline__ void wave_argmax(float& val, int& idx) {
#pragma unroll
  for (int off = 1; off < 64; off <<= 1) {
    float ov = __shfl_xor(val, off, 64);
    int oi = __shfl_xor(idx, off, 64);
    if (ov > val || (ov == val && oi < idx)) { val = ov; idx = oi; }
  }
}

__device__ __forceinline__ float wave_sum(float v) {
#pragma unroll
  for (int off = 1; off < 64; off <<= 1) v += __shfl_xor(v, off, 64);
  return v;
}

// ---------------------------------------------------------------------------
// FALLBACK GEMM (fp32 vector): Z = X @ W + b — used if ws too small.
// ---------------------------------------------------------------------------
__global__ __launch_bounds__(256) void gemm_kernel(
    const float* __restrict__ X, const float* __restrict__ W,
    const float* __restrict__ Bv, float* __restrict__ Z) {
  __shared__ float sA[16][68];
  __shared__ float sB[16][68];
  const int tid = threadIdx.x;
  const int rowTile = blockIdx.y * 64;
  const int colTile = blockIdx.x * 64;
  const int tx = tid & 15, ty = tid >> 4;
  float acc[4][4] = {};
  const int aRow = tid >> 2, aK = (tid & 3) << 2;
  const int bK = tid >> 4, bC = (tid & 15) << 2;
  const bool fullCol = (colTile + 64) <= CC;
  for (int k0 = 0; k0 < DD; k0 += 16) {
    const float4 av = *(const float4*)&X[(size_t)(rowTile + aRow) * DD + k0 + aK];
    sA[aK + 0][aRow] = av.x;
    sA[aK + 1][aRow] = av.y;
    sA[aK + 2][aRow] = av.z;
    sA[aK + 3][aRow] = av.w;
    float4 bv;
    if (fullCol) {
      bv = *(const float4*)&W[(size_t)(k0 + bK) * CC + colTile + bC];
    } else {
      const int c0 = colTile + bC;
      bv.x = (c0 + 0 < CC) ? W[(size_t)(k0 + bK) * CC + c0 + 0] : 0.f;
      bv.y = (c0 + 1 < CC) ? W[(size_t)(k0 + bK) * CC + c0 + 1] : 0.f;
      bv.z = (c0 + 2 < CC) ? W[(size_t)(k0 + bK) * CC + c0 + 2] : 0.f;
      bv.w = (c0 + 3 < CC) ? W[(size_t)(k0 + bK) * CC + c0 + 3] : 0.f;
    }
    *(float4*)&sB[bK][bC] = bv;
    __syncthreads();
#pragma unroll
    for (int kk = 0; kk < 16; ++kk) {
      const float4 a4 = *(const float4*)&sA[kk][ty << 2];
      const float4 b4 = *(const float4*)&sB[kk][tx << 2];
      const float ar[4] = {a4.x, a4.y, a4.z, a4.w};
      const float br[4] = {b4.x, b4.y, b4.z, b4.w};
#pragma unroll
      for (int i = 0; i < 4; ++i)
#pragma unroll
        for (int j = 0; j < 4; ++j) acc[i][j] = fmaf(ar[i], br[j], acc[i][j]);
    }
    __syncthreads();
  }
#pragma unroll
  for (int i = 0; i < 4; ++i) {
    const int r = rowTile + (ty << 2) + i;
#pragma unroll
    for (int j = 0; j < 4; ++j) {
      const int c = colTile + (tx << 2) + j;
      if (c < CC) Z[(size_t)r * CC + c] = acc[i][j] + Bv[c];
    }
  }
}

// ---------------------------------------------------------------------------
// convA: A fp32 [4096x2048] -> Ah, Al bf16 (hi + residual-lo split)
// ---------------------------------------------------------------------------
__global__ __launch_bounds__(256) void conv_a(
    const float* __restrict__ A, unsigned short* __restrict__ Ah,
    unsigned short* __restrict__ Al) {
  const int i = (blockIdx.x * 256 + threadIdx.x) * 4;
  const float4 v = *(const float4*)(A + i);
  ushort4 h, l;
  h.x = f2bf(v.x); l.x = f2bf(v.x - bf2f(h.x));
  h.y = f2bf(v.y); l.y = f2bf(v.y - bf2f(h.y));
  h.z = f2bf(v.z); l.z = f2bf(v.z - bf2f(h.z));
  h.w = f2bf(v.w); l.w = f2bf(v.w - bf2f(h.w));
  *(ushort4*)(Ah + i) = h;
  *(ushort4*)(Al + i) = l;
}

// ---------------------------------------------------------------------------
// convB: W fp32 [2048x1000] -> Bht, Blt bf16 TRANSPOSED [1000][2048]
// (32x32 LDS tile transpose; coalesced both sides)
// ---------------------------------------------------------------------------
__global__ __launch_bounds__(256) void conv_b(
    const float* __restrict__ B, unsigned short* __restrict__ Bht,
    unsigned short* __restrict__ Blt) {
  __shared__ float t[32][33];
  const int kt = blockIdx.x * 32;   // 64 k-tiles
  const int nt = blockIdx.y * 32;   // 32 n-tiles (covers 1024 >= 1000)
  const int tx = threadIdx.x & 31, ty = threadIdx.x >> 5;  // 32 x 8
#pragma unroll
  for (int r = 0; r < 4; ++r) {
    const int k = kt + ty + r * 8, n = nt + tx;
    t[ty + r * 8][tx] = (n < CC) ? B[(size_t)k * CC + n] : 0.f;
  }
  __syncthreads();
#pragma unroll
  for (int r = 0; r < 4; ++r) {
    const int n = nt + ty + r * 8, k = kt + tx;
    if (n < CC) {
      const float v = t[tx][ty + r * 8];
      const unsigned short h = f2bf(v);
      Bht[(size_t)n * DD + k] = h;
      Blt[(size_t)n * DD + k] = f2bf(v - bf2f(h));
    }
  }
}

// ---------------------------------------------------------------------------
// MFMA GEMM, fp32-accurate via 3-split packed K:
//   Z = Ah*Bh (k'=0..2047) + Al*Bh (2048..4095) + Ah*Bl (4096..6143) + bias
// 256 blocks (8 n-tiles x 32 m-tiles), 256 thr (4 waves, 2x2 quadrants of
// the 128x128 tile; each wave 4x4 tiles of 16x16x32 bf16 MFMA).
// LDS pitch 68 ushorts: rows 8B-aligned for b64 frag loads, dword-stride
// 34 == 2 mod 32 -> ~2-3-way conflicts (near-free per m136).
// ---------------------------------------------------------------------------
#define PITCH 68
__global__ __launch_bounds__(256) void mfma_gemm(
    const unsigned short* __restrict__ Ah, const unsigned short* __restrict__ Al,
    const unsigned short* __restrict__ Bht, const unsigned short* __restrict__ Blt,
    const float* __restrict__ Bv, float* __restrict__ Z) {
  __shared__ unsigned short sA[128 * PITCH];
  __shared__ unsigned short sB[128 * PITCH];
  const int tid = threadIdx.x;
  const int n0 = blockIdx.x * 128;  // 0..896
  const int m0 = blockIdx.y * 128;  // 0..3968
  const int wave = tid >> 6, lane = tid & 63;
  const int wr = (wave >> 1) * 64;  // wave row offset in 128-tile
  const int wc = (wave & 1) * 64;   // wave col offset
  const int fr = lane & 15;         // frag row (A) / col (B)
  const int fq = lane >> 4;         // quad -> k chunk

  f32x4 acc[4][4] = {};

  const int sr = tid >> 1;          // staging row 0..127
  const int sc = (tid & 1) * 32;    // staging k-chunk (32 ushorts)
  const bool bvalid = (n0 + sr) < CC;

  union Frag {
    short8 v;
    uint2 u[2];
  };

  for (int s = 0; s < 96; ++s) {
    const int kp = s << 6;
    const int seg = kp >> 11;
    const int kk = kp & 2047;
    const unsigned short* Asrc = (seg == 1) ? Al : Ah;
    const unsigned short* Bsrc = (seg == 2) ? Blt : Bht;

    uint4 av0, av1, av2, av3, bv0, bv1, bv2, bv3;
    {
      const uint4* gA =
          (const uint4*)(Asrc + (size_t)(m0 + sr) * DD + kk + sc);
      av0 = gA[0]; av1 = gA[1]; av2 = gA[2]; av3 = gA[3];
      if (bvalid) {
        const uint4* gB =
            (const uint4*)(Bsrc + (size_t)(n0 + sr) * DD + kk + sc);
        bv0 = gB[0]; bv1 = gB[1]; bv2 = gB[2]; bv3 = gB[3];
      } else {
        bv0 = bv1 = bv2 = bv3 = make_uint4(0, 0, 0, 0);
      }
    }
    __syncthreads();  // previous step's frag reads complete
    {
      unsigned short* dA = sA + sr * PITCH + sc;
      ((uint2*)(dA + 0))[0] = make_uint2(av0.x, av0.y);
      ((uint2*)(dA + 4))[0] = make_uint2(av0.z, av0.w);
      ((uint2*)(dA + 8))[0] = make_uint2(av1.x, av1.y);
      ((uint2*)(dA + 12))[0] = make_uint2(av1.z, av1.w);
      ((uint2*)(dA + 16))[0] = make_uint2(av2.x, av2.y);
      ((uint2*)(dA + 20))[0] = make_uint2(av2.z, av2.w);
      ((uint2*)(dA + 24))[0] = make_uint2(av3.x, av3.y);
      ((uint2*)(dA + 28))[0] = make_uint2(av3.z, av3.w);
      unsigned short* dB = sB + sr * PITCH + sc;
      ((uint2*)(dB + 0))[0] = make_uint2(bv0.x, bv0.y);
      ((uint2*)(dB + 4))[0] = make_uint2(bv0.z, bv0.w);
      ((uint2*)(dB + 8))[0] = make_uint2(bv1.x, bv1.y);
      ((uint2*)(dB + 12))[0] = make_uint2(bv1.z, bv1.w);
      ((uint2*)(dB + 16))[0] = make_uint2(bv2.x, bv2.y);
      ((uint2*)(dB + 20))[0] = make_uint2(bv2.z, bv2.w);
      ((uint2*)(dB + 24))[0] = make_uint2(bv3.x, bv3.y);
      ((uint2*)(dB + 28))[0] = make_uint2(bv3.z, bv3.w);
    }
    __syncthreads();

#pragma unroll
    for (int h = 0; h < 2; ++h) {
      const int ko = h * 32 + fq * 8;
      Frag a4[4], b4[4];
#pragma unroll
      for (int mt = 0; mt < 4; ++mt) {
        const unsigned short* p = sA + (wr + mt * 16 + fr) * PITCH + ko;
        a4[mt].u[0] = *(const uint2*)(p);
        a4[mt].u[1] = *(const uint2*)(p + 4);
      }
#pragma unroll
      for (int nt = 0; nt < 4; ++nt) {
        const unsigned short* p = sB + (wc + nt * 16 + fr) * PITCH + ko;
        b4[nt].u[0] = *(const uint2*)(p);
        b4[nt].u[1] = *(const uint2*)(p + 4);
      }
#pragma unroll
      for (int mt = 0; mt < 4; ++mt)
#pragma unroll
        for (int nt = 0; nt < 4; ++nt)
          acc[mt][nt] = __builtin_amdgcn_mfma_f32_16x16x32_bf16(
              a4[mt].v, b4[nt].v, acc[mt][nt], 0, 0, 0);
    }
  }

  // Epilogue: C/D layout col=lane&15, row=(lane>>4)*4+reg
#pragma unroll
  for (int nt = 0; nt < 4; ++nt) {
    const int col = n0 + wc + nt * 16 + fr;
    if (col < CC) {
      const float bb = Bv[col];
#pragma unroll
      for (int mt = 0; mt < 4; ++mt) {
        const int rbase = m0 + wr + mt * 16 + fq * 4;
#pragma unroll
        for (int r = 0; r < 4; ++r)
          Z[(size_t)(rbase + r) * CC + col] = acc[mt][nt][r] + bb;
      }
    }
  }
}

// ---------------------------------------------------------------------------
// Per-row stats from z (unchanged from R8).
// ---------------------------------------------------------------------------
__global__ __launch_bounds__(256) void stats_kernel(
    const float* __restrict__ Z, int* __restrict__ Y,
    float* __restrict__ Lt, float* __restrict__ Pt) {
  const int wave = threadIdx.x >> 6, lane = threadIdx.x & 63;
  const int row = blockIdx.x * 4 + wave;
  float uv[16];
#pragma unroll
  for (int k = 0; k < 16; ++k) {
    const int j = lane + (k << 6);
    uv[k] = (j < CC) ? Z[(size_t)row * CC + j] : -__builtin_inff();
  }
  float mx = uv[0];
  int ai = lane;
#pragma unroll
  for (int k = 1; k < 16; ++k) {
    const int j = lane + (k << 6);
    if (uv[k] > mx) { mx = uv[k]; ai = j; }
  }
  wave_argmax(mx, ai);
  float sum = 0.f;
#pragma unroll
  for (int k = 0; k < 16; ++k) sum += fexp(uv[k] - mx);
  sum = wave_sum(sum);
  if (lane == 0) {
    const float lse = mx + flog(sum);
    const float lorg = lse - mx;
    const float latr = (floorf(lorg / 6.0f) + 0.5f) * 6.0f;
    const float lt =
        lorg - 6.0f * sinf(3.14159265358979323846f *
                           (1.0f - 2.0f * (lorg - latr) / 6.0f));
    Y[row] = ai;
    Lt[row] = lt;
    Pt[row] = frcp(sum);
  }
}

// ---------------------------------------------------------------------------
// Bitonic sort of p_trg (4096) in LDS, single block (unchanged).
// ---------------------------------------------------------------------------
__global__ __launch_bounds__(1024) void sort_kernel(
    const float* __restrict__ P, float* __restrict__ Out) {
  __shared__ float s[4096];
  const int tid = threadIdx.x;
  for (int i = tid; i < 4096; i += 1024) s[i] = P[i];
  __syncthreads();
  for (int k = 2; k <= 4096; k <<= 1) {
    for (int j = k >> 1; j > 0; j >>= 1) {
      for (int i = tid; i < 4096; i += 1024) {
        const int ixj = i ^ j;
        if (ixj > i) {
          const float a = s[i], b = s[ixj];
          const bool up = ((i & k) == 0);
          if (up ? (a > b) : (a < b)) { s[i] = b; s[ixj] = a; }
        }
      }
      __syncthreads();
    }
  }
  for (int i = tid; i < 4096; i += 1024) Out[i] = s[i];
}

// ---------------------------------------------------------------------------
// Cooperative optimizer (unchanged from R8 — passing at 733 us).
// ---------------------------------------------------------------------------
__global__ __launch_bounds__(1024, 1) void opt_kernel(
    float* __restrict__ ZU, const int* __restrict__ Yarr,
    const float* __restrict__ Ltrg, const float* __restrict__ Sorted,
    unsigned long long* __restrict__ Slots) {
  const int tid = threadIdx.x;
  const int wave = tid >> 6, lane = tid & 63;
  const int row = blockIdx.x * 16 + wave;

  __shared__ float s_sorted[4096];
  __shared__ float s_coarse[64];
  __shared__ float s_cval[2][16];
  __shared__ int s_cidx[2][16];
  __shared__ float s_coef[2];
  __shared__ int s_rc[2];
  __shared__ int s_arrive[2];
  __shared__ int s_done[2];

  for (int i = tid; i < 4096; i += 1024) s_sorted[i] = Sorted[i];
  if (tid < 64) s_coarse[tid] = Sorted[tid << 6];
  if (tid == 0) {
    s_arrive[0] = 0;
    s_arrive[1] = 0;
    s_done[0] = 0;
    s_done[1] = 0;
  }

  float u[16], m[16], v[16], e[16];
#pragma unroll
  for (int k = 0; k < 16; ++k) {
    const int j = lane + (k << 6);
    u[k] = (j < CC) ? ZU[(size_t)row * CC + j] : -__builtin_inff();
    m[k] = 0.f;
    v[k] = 0.f;
  }
  const int y = Yarr[row];
  const float ltrg = Ltrg[row];
  const int ky = y >> 6, ly = y & 63;

  float pb1 = 1.0f, pb2 = 1.0f;
  __syncthreads();

#pragma unroll 1
  for (int t = 1; t <= 100; ++t) {
    const int p = t & 1;
    pb1 *= 0.9f;
    pb2 *= 0.999f;
    const float im1 = frcp(1.0f - pb1);
    const float im2 = frcp(1.0f - pb2);

    float mx = u[0];
    int ai = lane;
#pragma unroll
    for (int k = 1; k < 16; ++k) {
      const int j = lane + (k << 6);
      if (u[k] > mx) { mx = u[k]; ai = j; }
    }
    wave_argmax(mx, ai);
    float sum = 0.f;
#pragma unroll
    for (int k = 0; k < 16; ++k) {
      e[k] = fexp(u[k] - mx);
      sum += e[k];
    }
    sum = wave_sum(sum);
    const float lse = mx + flog(sum);
    float uyl = 0.f;
#pragma unroll
    for (int k = 0; k < 16; ++k) uyl = (k == ky) ? u[k] : uyl;
    const float uy = __shfl(uyl, ly, 64);
    const float ce = lse - uy;
    const float pmax = frcp(sum);
    const float a = (ce > ltrg) ? 1.0f : ((ce < ltrg) ? -1.0f : 0.0f);

    if (lane == 0) {
      s_cval[p][wave] = pmax;
      s_cidx[p][wave] = (row << 10) | ai;
      __hip_atomic_fetch_add(&s_arrive[p], 1, __ATOMIC_RELEASE,
                             __HIP_MEMORY_SCOPE_WORKGROUP);
    }
    const int target = 16 * ((t >> 1) + (t & 1));
    while (__hip_atomic_load(&s_arrive[p], __ATOMIC_ACQUIRE,
                             __HIP_MEMORY_SCOPE_WORKGROUP) < target) {
    }

    float bv = s_cval[p][0];
    int bi = s_cidx[p][0];
#pragma unroll
    for (int w = 1; w < 16; ++w) {
      const float ov = s_cval[p][w];
      const int oi = s_cidx[p][w];
      if (ov > bv || (ov == bv && oi < bi)) { bv = ov; bi = oi; }
    }
    const int candw = (bi >> 10) & 15;
    const bool iscand = (wave == candw);

    unsigned long long* slot_buf = &Slots[p * 256];
    if (tid == 0) {
      const unsigned long long pack =
          ((unsigned long long)__float_as_uint(bv) << 32) |
          (unsigned)((t << 24) | bi);
      __hip_atomic_store(&slot_buf[blockIdx.x], pack, __ATOMIC_RELAXED,
                         __HIP_MEMORY_SCOPE_AGENT);
    }

    auto adam_update = [&](bool with_t2, float coef, int cstar) {
#pragma unroll
      for (int k = 0; k < 16; ++k) {
        const int j = lane + (k << 6);
        const float p2 = e[k] * pmax;
        float g = a * (p2 - ((j == y) ? 1.0f : 0.0f));
        if (with_t2) g += coef * (((j == cstar) ? 1.0f : 0.0f) - p2);
        u[k] *= 0.999f;
        m[k] = 0.9f * m[k] + 0.1f * g;
        v[k] = 0.999f * v[k] + 0.001f * g * g;
        const float mh = m[k] * im1;
        const float vh = v[k] * im2;
        u[k] -= 0.1f * mh * frcp(fsqrt(vh) + 1e-8f);
      }
    };

    if (!iscand && wave != 0) adam_update(false, 0.f, 0);

    if (wave == 0) {
      if (!iscand) adam_update(false, 0.f, 0);
      unsigned long long pv[4];
      unsigned fresh = 0u;
      while (fresh != 0xFu) {
#pragma unroll
        for (int q = 0; q < 4; ++q) {
          if (!(fresh & (1u << q))) {
            const unsigned long long pk = __hip_atomic_load(
                &slot_buf[lane + (q << 6)], __ATOMIC_RELAXED,
                __HIP_MEMORY_SCOPE_AGENT);
            if ((unsigned)((pk >> 24) & 0xFFu) == (unsigned)t) {
              pv[q] = pk;
              fresh |= 1u << q;
            }
          }
        }
        if (fresh != 0xFu) __builtin_amdgcn_s_sleep(1);
      }
      float gv = -1.0f;
      int gi = 0x7fffffff;
#pragma unroll
      for (int q = 0; q < 4; ++q) {
        const float ov = __uint_as_float((unsigned)(pv[q] >> 32));
        const int oi = (int)(pv[q] & 0x3FFFFFu);
        if (ov > gv || (ov == gv && oi < gi)) { gv = ov; gi = oi; }
      }
      wave_argmax(gv, gi);
      const float ss = gv;
      const float v1 = s_coarse[lane];
      const int c1 = __popcll(__ballot(v1 < ss));
      int nlt = 0;
      if (c1 > 0) {
        const float v2 = s_sorted[((c1 - 1) << 6) + lane];
        nlt = ((c1 - 1) << 6) + __popcll(__ballot(v2 < ss));
      }
      const int c2 = __popcll(__ballot(v1 <= ss));
      int nle = 0;
      if (c2 > 0) {
        const float v3 = s_sorted[((c2 - 1) << 6) + lane];
        nle = ((c2 - 1) << 6) + __popcll(__ballot(v3 <= ss));
      }
      const int S = nlt - (4096 - nle);
      if (lane == 0) {
        s_coef[p] = 5.0f * (float)S * ss;
        s_rc[p] = gi;
        __hip_atomic_store(&s_done[p], t, __ATOMIC_RELEASE,
                           __HIP_MEMORY_SCOPE_WORKGROUP);
      }
    }

    if (iscand) {
      while (__hip_atomic_load(&s_done[p], __ATOMIC_ACQUIRE,
                               __HIP_MEMORY_SCOPE_WORKGROUP) < t) {
      }
      const int rc = s_rc[p];
      const bool win = ((rc >> 10) == row);
      adam_update(win, s_coef[p], rc & 1023);
    }
  }

#pragma unroll
  for (int k = 0; k < 16; ++k) {
    const int j = lane + (k << 6);
    if (j < CC) ZU[(size_t)row * CC + j] = u[k];
  }
}

// ---------------------------------------------------------------------------
extern "C" void kernel_launch(void* const* d_in, const int* in_sizes, int n_in,
                              void* d_out, int out_size, void* d_ws,
                              size_t ws_size, hipStream_t stream) {
  const float* x = (const float*)d_in[0];
  const float* W = (const float*)d_in[1];
  const float* b = (const float*)d_in[2];
  float* z = (float*)d_out;

  char* ws = (char*)d_ws;
  int* y_arr = (int*)ws;                              // 16 KB
  float* ltrg_arr = (float*)(ws + (16 << 10));        // 16 KB
  float* ptrg_arr = (float*)(ws + (32 << 10));        // 16 KB
  float* sorted = (float*)(ws + (48 << 10));          // 16 KB
  unsigned long long* slots =
      (unsigned long long*)(ws + (64 << 10));         // 4 KB (2 x 256)

  // bf16-split GEMM scratch (beyond 1 MB)
  const size_t A_BYTES = (size_t)BB * DD * 2;  // 16.78 MB per copy
  const size_t B_BYTES = (size_t)CC * DD * 2;  // 4.10 MB per copy
  unsigned short* AhP = (unsigned short*)(ws + (1 << 20));
  unsigned short* AlP = (unsigned short*)(ws + (1 << 20) + A_BYTES);
  unsigned short* BhP = (unsigned short*)(ws + (1 << 20) + 2 * A_BYTES);
  unsigned short* BlP =
      (unsigned short*)(ws + (1 << 20) + 2 * A_BYTES + B_BYTES);
  const bool use_mfma = ws_size >= ((size_t)44 << 20);

  if (use_mfma) {
    conv_a<<<dim3(8192), 256, 0, stream>>>(x, AhP, AlP);
    conv_b<<<dim3(64, 32), 256, 0, stream>>>(W, BhP, BlP);
    mfma_gemm<<<dim3(8, 32), 256, 0, stream>>>(AhP, AlP, BhP, BlP, b, z);
  } else {
    gemm_kernel<<<dim3(16, 64), 256, 0, stream>>>(x, W, b, z);
  }
  stats_kernel<<<dim3(1024), 256, 0, stream>>>(z, y_arr, ltrg_arr, ptrg_arr);
  sort_kernel<<<dim3(1), 1024, 0, stream>>>(ptrg_arr, sorted);

  void* args[5] = {&z, &y_arr, &ltrg_arr, &sorted, &slots};
  hipLaunchCooperativeKernel((const void*)opt_kernel, dim3(256), dim3(1024),
                             args, 0u, stream);
}

// Round 10
// 972.892 us; speedup vs baseline: 2.8099x; 1.0429x over previous
//
#include <hip/hip_runtime.h>

// Problem dims
#define BB 4096
#define DD 2048
#define CC 1000

typedef short short8 __attribute__((ext_vector_type(8)));
typedef float f32x4 __attribute__((ext_vector_type(4)));

// RNE fp32 -> bf16 (inputs finite; no NaN handling needed)
__device__ __forceinline__ unsigned short f2bf(float x) {
  unsigned u = __float_as_uint(x);
  unsigned r = (u + 0x7FFFu + ((u >> 16) & 1u)) >> 16;
  return (unsigned short)r;
}
__device__ __forceinline__ float bf2f(unsigned short h) {
  return __uint_as_float(((unsigned)h) << 16);
}

__device__ __forceinline__ float fexp(float x) { return __expf(x); }
__device__ __forceinline__ float flog(float x) { return __logf(x); }
__device__ __forceinline__ float frcp(float x) {
  return __builtin_amdgcn_rcpf(x);
}
__device__ __forceinline__ float fsqrt(float x) {
  return __builtin_amdgcn_sqrtf(x);
}

__device__ __forceinline__ void wave_argmax(float& val, int& idx) {
#pragma unroll
  for (int off = 1; off < 64; off <<= 1) {
    float ov = __shfl_xor(val, off, 64);
    int oi = __shfl_xor(idx, off, 64);
    if (ov > val || (ov == val && oi < idx)) { val = ov; idx = oi; }
  }
}

__device__ __forceinline__ float wave_sum(float v) {
#pragma unroll
  for (int off = 1; off < 64; off <<= 1) v += __shfl_xor(v, off, 64);
  return v;
}

// ---------------------------------------------------------------------------
// FALLBACK GEMM (fp32 vector): Z = X @ W + b — used if ws too small.
// ---------------------------------------------------------------------------
__global__ __launch_bounds__(256) void gemm_kernel(
    const float* __restrict__ X, const float* __restrict__ W,
    const float* __restrict__ Bv, float* __restrict__ Z) {
  __shared__ float sA[16][68];
  __shared__ float sB[16][68];
  const int tid = threadIdx.x;
  const int rowTile = blockIdx.y * 64;
  const int colTile = blockIdx.x * 64;
  const int tx = tid & 15, ty = tid >> 4;
  float acc[4][4] = {};
  const int aRow = tid >> 2, aK = (tid & 3) << 2;
  const int bK = tid >> 4, bC = (tid & 15) << 2;
  const bool fullCol = (colTile + 64) <= CC;
  for (int k0 = 0; k0 < DD; k0 += 16) {
    const float4 av = *(const float4*)&X[(size_t)(rowTile + aRow) * DD + k0 + aK];
    sA[aK + 0][aRow] = av.x;
    sA[aK + 1][aRow] = av.y;
    sA[aK + 2][aRow] = av.z;
    sA[aK + 3][aRow] = av.w;
    float4 bv;
    if (fullCol) {
      bv = *(const float4*)&W[(size_t)(k0 + bK) * CC + colTile + bC];
    } else {
      const int c0 = colTile + bC;
      bv.x = (c0 + 0 < CC) ? W[(size_t)(k0 + bK) * CC + c0 + 0] : 0.f;
      bv.y = (c0 + 1 < CC) ? W[(size_t)(k0 + bK) * CC + c0 + 1] : 0.f;
      bv.z = (c0 + 2 < CC) ? W[(size_t)(k0 + bK) * CC + c0 + 2] : 0.f;
      bv.w = (c0 + 3 < CC) ? W[(size_t)(k0 + bK) * CC + c0 + 3] : 0.f;
    }
    *(float4*)&sB[bK][bC] = bv;
    __syncthreads();
#pragma unroll
    for (int kk = 0; kk < 16; ++kk) {
      const float4 a4 = *(const float4*)&sA[kk][ty << 2];
      const float4 b4 = *(const float4*)&sB[kk][tx << 2];
      const float ar[4] = {a4.x, a4.y, a4.z, a4.w};
      const float br[4] = {b4.x, b4.y, b4.z, b4.w};
#pragma unroll
      for (int i = 0; i < 4; ++i)
#pragma unroll
        for (int j = 0; j < 4; ++j) acc[i][j] = fmaf(ar[i], br[j], acc[i][j]);
    }
    __syncthreads();
  }
#pragma unroll
  for (int i = 0; i < 4; ++i) {
    const int r = rowTile + (ty << 2) + i;
#pragma unroll
    for (int j = 0; j < 4; ++j) {
      const int c = colTile + (tx << 2) + j;
      if (c < CC) Z[(size_t)r * CC + c] = acc[i][j] + Bv[c];
    }
  }
}

// ---------------------------------------------------------------------------
// convA: A fp32 [4096x2048] -> Ah, Al bf16 (hi + residual-lo split)
// ---------------------------------------------------------------------------
__global__ __launch_bounds__(256) void conv_a(
    const float* __restrict__ A, unsigned short* __restrict__ Ah,
    unsigned short* __restrict__ Al) {
  const int i = (blockIdx.x * 256 + threadIdx.x) * 4;
  const float4 v = *(const float4*)(A + i);
  ushort4 h, l;
  h.x = f2bf(v.x); l.x = f2bf(v.x - bf2f(h.x));
  h.y = f2bf(v.y); l.y = f2bf(v.y - bf2f(h.y));
  h.z = f2bf(v.z); l.z = f2bf(v.z - bf2f(h.z));
  h.w = f2bf(v.w); l.w = f2bf(v.w - bf2f(h.w));
  *(ushort4*)(Ah + i) = h;
  *(ushort4*)(Al + i) = l;
}

// ---------------------------------------------------------------------------
// convB: W fp32 [2048x1000] -> Bht, Blt bf16 TRANSPOSED [1000][2048]
// ---------------------------------------------------------------------------
__global__ __launch_bounds__(256) void conv_b(
    const float* __restrict__ B, unsigned short* __restrict__ Bht,
    unsigned short* __restrict__ Blt) {
  __shared__ float t[32][33];
  const int kt = blockIdx.x * 32;
  const int nt = blockIdx.y * 32;
  const int tx = threadIdx.x & 31, ty = threadIdx.x >> 5;
#pragma unroll
  for (int r = 0; r < 4; ++r) {
    const int k = kt + ty + r * 8, n = nt + tx;
    t[ty + r * 8][tx] = (n < CC) ? B[(size_t)k * CC + n] : 0.f;
  }
  __syncthreads();
#pragma unroll
  for (int r = 0; r < 4; ++r) {
    const int n = nt + ty + r * 8, k = kt + tx;
    if (n < CC) {
      const float v = t[tx][ty + r * 8];
      const unsigned short h = f2bf(v);
      Bht[(size_t)n * DD + k] = h;
      Blt[(size_t)n * DD + k] = f2bf(v - bf2f(h));
    }
  }
}

// ---------------------------------------------------------------------------
// MFMA GEMM, fp32-accurate via 3-split packed K (unchanged from R9, passing).
// ---------------------------------------------------------------------------
#define PITCH 68
__global__ __launch_bounds__(256) void mfma_gemm(
    const unsigned short* __restrict__ Ah, const unsigned short* __restrict__ Al,
    const unsigned short* __restrict__ Bht, const unsigned short* __restrict__ Blt,
    const float* __restrict__ Bv, float* __restrict__ Z) {
  __shared__ unsigned short sA[128 * PITCH];
  __shared__ unsigned short sB[128 * PITCH];
  const int tid = threadIdx.x;
  const int n0 = blockIdx.x * 128;
  const int m0 = blockIdx.y * 128;
  const int wave = tid >> 6, lane = tid & 63;
  const int wr = (wave >> 1) * 64;
  const int wc = (wave & 1) * 64;
  const int fr = lane & 15;
  const int fq = lane >> 4;

  f32x4 acc[4][4] = {};

  const int sr = tid >> 1;
  const int sc = (tid & 1) * 32;
  const bool bvalid = (n0 + sr) < CC;

  union Frag {
    short8 v;
    uint2 u[2];
  };

  for (int s = 0; s < 96; ++s) {
    const int kp = s << 6;
    const int seg = kp >> 11;
    const int kk = kp & 2047;
    const unsigned short* Asrc = (seg == 1) ? Al : Ah;
    const unsigned short* Bsrc = (seg == 2) ? Blt : Bht;

    uint4 av0, av1, av2, av3, bv0, bv1, bv2, bv3;
    {
      const uint4* gA =
          (const uint4*)(Asrc + (size_t)(m0 + sr) * DD + kk + sc);
      av0 = gA[0]; av1 = gA[1]; av2 = gA[2]; av3 = gA[3];
      if (bvalid) {
        const uint4* gB =
            (const uint4*)(Bsrc + (size_t)(n0 + sr) * DD + kk + sc);
        bv0 = gB[0]; bv1 = gB[1]; bv2 = gB[2]; bv3 = gB[3];
      } else {
        bv0 = bv1 = bv2 = bv3 = make_uint4(0, 0, 0, 0);
      }
    }
    __syncthreads();
    {
      unsigned short* dA = sA + sr * PITCH + sc;
      ((uint2*)(dA + 0))[0] = make_uint2(av0.x, av0.y);
      ((uint2*)(dA + 4))[0] = make_uint2(av0.z, av0.w);
      ((uint2*)(dA + 8))[0] = make_uint2(av1.x, av1.y);
      ((uint2*)(dA + 12))[0] = make_uint2(av1.z, av1.w);
      ((uint2*)(dA + 16))[0] = make_uint2(av2.x, av2.y);
      ((uint2*)(dA + 20))[0] = make_uint2(av2.z, av2.w);
      ((uint2*)(dA + 24))[0] = make_uint2(av3.x, av3.y);
      ((uint2*)(dA + 28))[0] = make_uint2(av3.z, av3.w);
      unsigned short* dB = sB + sr * PITCH + sc;
      ((uint2*)(dB + 0))[0] = make_uint2(bv0.x, bv0.y);
      ((uint2*)(dB + 4))[0] = make_uint2(bv0.z, bv0.w);
      ((uint2*)(dB + 8))[0] = make_uint2(bv1.x, bv1.y);
      ((uint2*)(dB + 12))[0] = make_uint2(bv1.z, bv1.w);
      ((uint2*)(dB + 16))[0] = make_uint2(bv2.x, bv2.y);
      ((uint2*)(dB + 20))[0] = make_uint2(bv2.z, bv2.w);
      ((uint2*)(dB + 24))[0] = make_uint2(bv3.x, bv3.y);
      ((uint2*)(dB + 28))[0] = make_uint2(bv3.z, bv3.w);
    }
    __syncthreads();

#pragma unroll
    for (int h = 0; h < 2; ++h) {
      const int ko = h * 32 + fq * 8;
      Frag a4[4], b4[4];
#pragma unroll
      for (int mt = 0; mt < 4; ++mt) {
        const unsigned short* p = sA + (wr + mt * 16 + fr) * PITCH + ko;
        a4[mt].u[0] = *(const uint2*)(p);
        a4[mt].u[1] = *(const uint2*)(p + 4);
      }
#pragma unroll
      for (int nt = 0; nt < 4; ++nt) {
        const unsigned short* p = sB + (wc + nt * 16 + fr) * PITCH + ko;
        b4[nt].u[0] = *(const uint2*)(p);
        b4[nt].u[1] = *(const uint2*)(p + 4);
      }
#pragma unroll
      for (int mt = 0; mt < 4; ++mt)
#pragma unroll
        for (int nt = 0; nt < 4; ++nt)
          acc[mt][nt] = __builtin_amdgcn_mfma_f32_16x16x32_bf16(
              a4[mt].v, b4[nt].v, acc[mt][nt], 0, 0, 0);
    }
  }

#pragma unroll
  for (int nt = 0; nt < 4; ++nt) {
    const int col = n0 + wc + nt * 16 + fr;
    if (col < CC) {
      const float bb = Bv[col];
#pragma unroll
      for (int mt = 0; mt < 4; ++mt) {
        const int rbase = m0 + wr + mt * 16 + fq * 4;
#pragma unroll
        for (int r = 0; r < 4; ++r)
          Z[(size_t)(rbase + r) * CC + col] = acc[mt][nt][r] + bb;
      }
    }
  }
}

// ---------------------------------------------------------------------------
// Per-row stats from z (unchanged from R8/R9).
// ---------------------------------------------------------------------------
__global__ __launch_bounds__(256) void stats_kernel(
    const float* __restrict__ Z, int* __restrict__ Y,
    float* __restrict__ Lt, float* __restrict__ Pt) {
  const int wave = threadIdx.x >> 6, lane = threadIdx.x & 63;
  const int row = blockIdx.x * 4 + wave;
  float uv[16];
#pragma unroll
  for (int k = 0; k < 16; ++k) {
    const int j = lane + (k << 6);
    uv[k] = (j < CC) ? Z[(size_t)row * CC + j] : -__builtin_inff();
  }
  float mx = uv[0];
  int ai = lane;
#pragma unroll
  for (int k = 1; k < 16; ++k) {
    const int j = lane + (k << 6);
    if (uv[k] > mx) { mx = uv[k]; ai = j; }
  }
  wave_argmax(mx, ai);
  float sum = 0.f;
#pragma unroll
  for (int k = 0; k < 16; ++k) sum += fexp(uv[k] - mx);
  sum = wave_sum(sum);
  if (lane == 0) {
    const float lse = mx + flog(sum);
    const float lorg = lse - mx;
    const float latr = (floorf(lorg / 6.0f) + 0.5f) * 6.0f;
    const float lt =
        lorg - 6.0f * sinf(3.14159265358979323846f *
                           (1.0f - 2.0f * (lorg - latr) / 6.0f));
    Y[row] = ai;
    Lt[row] = lt;
    Pt[row] = frcp(sum);
  }
}

// ---------------------------------------------------------------------------
// Bitonic sort of p_trg (4096) in LDS, single block (unchanged).
// ---------------------------------------------------------------------------
__global__ __launch_bounds__(1024) void sort_kernel(
    const float* __restrict__ P, float* __restrict__ Out) {
  __shared__ float s[4096];
  const int tid = threadIdx.x;
  for (int i = tid; i < 4096; i += 1024) s[i] = P[i];
  __syncthreads();
  for (int k = 2; k <= 4096; k <<= 1) {
    for (int j = k >> 1; j > 0; j >>= 1) {
      for (int i = tid; i < 4096; i += 1024) {
        const int ixj = i ^ j;
        if (ixj > i) {
          const float a = s[i], b = s[ixj];
          const bool up = ((i & k) == 0);
          if (up ? (a > b) : (a < b)) { s[i] = b; s[ixj] = a; }
        }
      }
      __syncthreads();
    }
  }
  for (int i = tid; i < 4096; i += 1024) Out[i] = s[i];
}

// ---------------------------------------------------------------------------
// Cooperative optimizer.  R10 changes vs R9 (both trajectory-bitwise-safe):
//  1. e[16] removed — the update recomputes fexp(u[k]-mx) (u[k] read before
//     modification => identical bits).  Live state 64->48 floats: fewer
//     VGPR<->AGPR round-trips in the hot loop.
//  2. wave 0 polls FIRST and publishes s_done, THEN does its own row update.
//     Removes wave0's 16-elem update from every block's candidate chain
//     (s_done -> redo -> phaseA(t+1) -> arrive -> slot(t+1)), which is the
//     grid-wide period.  Wave0-candidate case computes coef/rc locally (all
//     lanes hold S,ss,gi post-ballot — same bits as the LDS path).
// ---------------------------------------------------------------------------
__global__ __launch_bounds__(1024, 1) void opt_kernel(
    float* __restrict__ ZU, const int* __restrict__ Yarr,
    const float* __restrict__ Ltrg, const float* __restrict__ Sorted,
    unsigned long long* __restrict__ Slots) {
  const int tid = threadIdx.x;
  const int wave = tid >> 6, lane = tid & 63;
  const int row = blockIdx.x * 16 + wave;

  __shared__ float s_sorted[4096];
  __shared__ float s_coarse[64];
  __shared__ float s_cval[2][16];
  __shared__ int s_cidx[2][16];
  __shared__ float s_coef[2];
  __shared__ int s_rc[2];
  __shared__ int s_arrive[2];
  __shared__ int s_done[2];

  for (int i = tid; i < 4096; i += 1024) s_sorted[i] = Sorted[i];
  if (tid < 64) s_coarse[tid] = Sorted[tid << 6];
  if (tid == 0) {
    s_arrive[0] = 0;
    s_arrive[1] = 0;
    s_done[0] = 0;
    s_done[1] = 0;
  }

  float u[16], m[16], v[16];
#pragma unroll
  for (int k = 0; k < 16; ++k) {
    const int j = lane + (k << 6);
    u[k] = (j < CC) ? ZU[(size_t)row * CC + j] : -__builtin_inff();
    m[k] = 0.f;
    v[k] = 0.f;
  }
  const int y = Yarr[row];
  const float ltrg = Ltrg[row];
  const int ky = y >> 6, ly = y & 63;

  float pb1 = 1.0f, pb2 = 1.0f;
  __syncthreads();

#pragma unroll 1
  for (int t = 1; t <= 100; ++t) {
    const int p = t & 1;
    pb1 *= 0.9f;
    pb2 *= 0.999f;
    const float im1 = frcp(1.0f - pb1);
    const float im2 = frcp(1.0f - pb2);

    // ---- Phase A: row stats ----
    float mx = u[0];
    int ai = lane;
#pragma unroll
    for (int k = 1; k < 16; ++k) {
      const int j = lane + (k << 6);
      if (u[k] > mx) { mx = u[k]; ai = j; }
    }
    wave_argmax(mx, ai);
    float sum = 0.f;
#pragma unroll
    for (int k = 0; k < 16; ++k) sum += fexp(u[k] - mx);
    sum = wave_sum(sum);
    const float lse = mx + flog(sum);
    float uyl = 0.f;
#pragma unroll
    for (int k = 0; k < 16; ++k) uyl = (k == ky) ? u[k] : uyl;
    const float uy = __shfl(uyl, ly, 64);
    const float ce = lse - uy;
    const float pmax = frcp(sum);
    const float a = (ce > ltrg) ? 1.0f : ((ce < ltrg) ? -1.0f : 0.0f);

    // ---- publish candidate + arrive (release), then spin (acquire) ----
    if (lane == 0) {
      s_cval[p][wave] = pmax;
      s_cidx[p][wave] = (row << 10) | ai;
      __hip_atomic_fetch_add(&s_arrive[p], 1, __ATOMIC_RELEASE,
                             __HIP_MEMORY_SCOPE_WORKGROUP);
    }
    const int target = 16 * ((t >> 1) + (t & 1));
    while (__hip_atomic_load(&s_arrive[p], __ATOMIC_ACQUIRE,
                             __HIP_MEMORY_SCOPE_WORKGROUP) < target) {
    }

    // ---- every wave: redundant block-reduce of the 16 candidates ----
    float bv = s_cval[p][0];
    int bi = s_cidx[p][0];
#pragma unroll
    for (int w = 1; w < 16; ++w) {
      const float ov = s_cval[p][w];
      const int oi = s_cidx[p][w];
      if (ov > bv || (ov == bv && oi < bi)) { bv = ov; bi = oi; }
    }
    const int candw = (bi >> 10) & 15;
    const bool iscand = (wave == candw);

    unsigned long long* slot_buf = &Slots[p * 256];
    if (tid == 0) {
      const unsigned long long pack =
          ((unsigned long long)__float_as_uint(bv) << 32) |
          (unsigned)((t << 24) | bi);
      __hip_atomic_store(&slot_buf[blockIdx.x], pack, __ATOMIC_RELAXED,
                         __HIP_MEMORY_SCOPE_AGENT);
    }

    // exact AdamW step for this wave's row; term2 only when win.
    // p2 recomputed: identical bits to the former e[k]*pmax (u[k] unmodified
    // at read time, same fexp input).
    auto adam_update = [&](bool with_t2, float coef, int cstar) {
#pragma unroll
      for (int k = 0; k < 16; ++k) {
        const int j = lane + (k << 6);
        const float p2 = fexp(u[k] - mx) * pmax;
        float g = a * (p2 - ((j == y) ? 1.0f : 0.0f));
        if (with_t2) g += coef * (((j == cstar) ? 1.0f : 0.0f) - p2);
        u[k] *= 0.999f;
        m[k] = 0.9f * m[k] + 0.1f * g;
        v[k] = 0.999f * v[k] + 0.001f * g * g;
        const float mh = m[k] * im1;
        const float vh = v[k] * im2;
        u[k] -= 0.1f * mh * frcp(fsqrt(vh) + 1e-8f);
      }
    };

    // ---- non-candidate, non-poller waves: update now, run ahead ----
    if (!iscand && wave != 0) adam_update(false, 0.f, 0);

    // ---- wave 0: poll + publish s_done FIRST, then own update ----
    if (wave == 0) {
      unsigned long long pv[4];
      unsigned fresh = 0u;
      while (fresh != 0xFu) {
#pragma unroll
        for (int q = 0; q < 4; ++q) {
          if (!(fresh & (1u << q))) {
            const unsigned long long pk = __hip_atomic_load(
                &slot_buf[lane + (q << 6)], __ATOMIC_RELAXED,
                __HIP_MEMORY_SCOPE_AGENT);
            if ((unsigned)((pk >> 24) & 0xFFu) == (unsigned)t) {
              pv[q] = pk;
              fresh |= 1u << q;
            }
          }
        }
        if (fresh != 0xFu) __builtin_amdgcn_s_sleep(1);
      }
      float gv = -1.0f;
      int gi = 0x7fffffff;
#pragma unroll
      for (int q = 0; q < 4; ++q) {
        const float ov = __uint_as_float((unsigned)(pv[q] >> 32));
        const int oi = (int)(pv[q] & 0x3FFFFFu);
        if (ov > gv || (ov == gv && oi < gi)) { gv = ov; gi = oi; }
      }
      wave_argmax(gv, gi);
      const float ss = gv;
      const float v1 = s_coarse[lane];
      const int c1 = __popcll(__ballot(v1 < ss));
      int nlt = 0;
      if (c1 > 0) {
        const float v2 = s_sorted[((c1 - 1) << 6) + lane];
        nlt = ((c1 - 1) << 6) + __popcll(__ballot(v2 < ss));
      }
      const int c2 = __popcll(__ballot(v1 <= ss));
      int nle = 0;
      if (c2 > 0) {
        const float v3 = s_sorted[((c2 - 1) << 6) + lane];
        nle = ((c2 - 1) << 6) + __popcll(__ballot(v3 <= ss));
      }
      const int S = nlt - (4096 - nle);
      const float coef0 = 5.0f * (float)S * ss;  // all lanes: same bits
      if (lane == 0) {
        s_coef[p] = coef0;
        s_rc[p] = gi;
        __hip_atomic_store(&s_done[p], t, __ATOMIC_RELEASE,
                           __HIP_MEMORY_SCOPE_WORKGROUP);
      }
      // own row's update AFTER s_done is out (off the candidate chain)
      if (iscand) {
        adam_update((gi >> 10) == row, coef0, gi & 1023);
      } else {
        adam_update(false, 0.f, 0);
      }
    }

    // ---- candidate wave (not wave 0): wait, then deferred exact update ----
    if (iscand && wave != 0) {
      while (__hip_atomic_load(&s_done[p], __ATOMIC_ACQUIRE,
                               __HIP_MEMORY_SCOPE_WORKGROUP) < t) {
      }
      const int rc = s_rc[p];
      const bool win = ((rc >> 10) == row);
      adam_update(win, s_coef[p], rc & 1023);
    }
  }

#pragma unroll
  for (int k = 0; k < 16; ++k) {
    const int j = lane + (k << 6);
    if (j < CC) ZU[(size_t)row * CC + j] = u[k];
  }
}

// ---------------------------------------------------------------------------
extern "C" void kernel_launch(void* const* d_in, const int* in_sizes, int n_in,
                              void* d_out, int out_size, void* d_ws,
                              size_t ws_size, hipStream_t stream) {
  const float* x = (const float*)d_in[0];
  const float* W = (const float*)d_in[1];
  const float* b = (const float*)d_in[2];
  float* z = (float*)d_out;

  char* ws = (char*)d_ws;
  int* y_arr = (int*)ws;                              // 16 KB
  float* ltrg_arr = (float*)(ws + (16 << 10));        // 16 KB
  float* ptrg_arr = (float*)(ws + (32 << 10));        // 16 KB
  float* sorted = (float*)(ws + (48 << 10));          // 16 KB
  unsigned long long* slots =
      (unsigned long long*)(ws + (64 << 10));         // 4 KB (2 x 256)

  const size_t A_BYTES = (size_t)BB * DD * 2;
  const size_t B_BYTES = (size_t)CC * DD * 2;
  unsigned short* AhP = (unsigned short*)(ws + (1 << 20));
  unsigned short* AlP = (unsigned short*)(ws + (1 << 20) + A_BYTES);
  unsigned short* BhP = (unsigned short*)(ws + (1 << 20) + 2 * A_BYTES);
  unsigned short* BlP =
      (unsigned short*)(ws + (1 << 20) + 2 * A_BYTES + B_BYTES);
  const bool use_mfma = ws_size >= ((size_t)44 << 20);

  if (use_mfma) {
    conv_a<<<dim3(8192), 256, 0, stream>>>(x, AhP, AlP);
    conv_b<<<dim3(64, 32), 256, 0, stream>>>(W, BhP, BlP);
    mfma_gemm<<<dim3(8, 32), 256, 0, stream>>>(AhP, AlP, BhP, BlP, b, z);
  } else {
    gemm_kernel<<<dim3(16, 64), 256, 0, stream>>>(x, W, b, z);
  }
  stats_kernel<<<dim3(1024), 256, 0, stream>>>(z, y_arr, ltrg_arr, ptrg_arr);
  sort_kernel<<<dim3(1), 1024, 0, stream>>>(ptrg_arr, sorted);

  void* args[5] = {&z, &y_arr, &ltrg_arr, &sorted, &slots};
  hipLaunchCooperativeKernel((const void*)opt_kernel, dim3(256), dim3(1024),
                             args, 0u, stream);
}